// Round 1
// baseline (209.581 us; speedup 1.0000x reference)
//
#include <hip/hip_runtime.h>
#include <hip/hip_bf16.h>

#define DEV __device__ __forceinline__

typedef unsigned short u16;
typedef __attribute__((ext_vector_type(8))) short short8;  // 8 bf16 (4 VGPRs)
typedef __attribute__((ext_vector_type(4))) float f32x4;   // MFMA C/D

// ---------- helpers ----------
DEV u16 f2bf(float f) {               // RNE float -> bf16 bits
  union { float f; unsigned u; } v; v.f = f;
  unsigned r = v.u + 0x7FFFu + ((v.u >> 16) & 1u);
  return (u16)(r >> 16);
}

DEV void async_ld16(const u16* g, u16* l) {
  // global -> LDS direct, 16B per lane; dest = wave-uniform base + lane*16
  __builtin_amdgcn_global_load_lds((__attribute__((address_space(1))) void*)g,
                                   (__attribute__((address_space(3))) void*)l,
                                   16, 0, 0);
}

DEV f32x4 mfma16(short8 a, short8 b, f32x4 c) {
  return __builtin_amdgcn_mfma_f32_16x16x32_bf16(a, b, c, 0, 0, 0);
}

// ---------- constants ----------
// scores use exp2: fold 1/sqrt(64) * log2(e) into Q path; LORA_SCALE=2 into w_a rows
#define QSCALE (0.125f * 1.4426950408889634f)

// ---------- kernel 1: x fp32 -> bf16 ----------
__global__ __launch_bounds__(256) void k_conv_x(const float* __restrict__ x,
                                                u16* __restrict__ xb, int n4) {
  int i = blockIdx.x * 256 + threadIdx.x;
  int stride = gridDim.x * 256;
  for (; i < n4; i += stride) {
    float4 v = ((const float4*)x)[i];
    ushort4 o;
    o.x = f2bf(v.x); o.y = f2bf(v.y); o.z = f2bf(v.z); o.w = f2bf(v.w);
    ((ushort4*)xb)[i] = o;
  }
}

// ---------- kernel 2: combined projection weight W1 [256][2048] bf16 ----------
// rows 0-63 wq*QSCALE | 64-127 wk | 128-191 wv | 192-199 wq_a*2*QSCALE
// 200-207 wk_a*2 | 208-215 wv_a*2 | 216-255 zero
__global__ __launch_bounds__(256) void k_prep_w1(const float* __restrict__ wq,
    const float* __restrict__ wk, const float* __restrict__ wv,
    const float* __restrict__ wqa, const float* __restrict__ wka,
    const float* __restrict__ wva, u16* __restrict__ W1) {
  const int row = blockIdx.x;
  const float* src = nullptr; float sc = 1.f;
  if (row < 64)       { src = wq  + row*2048;       sc = QSCALE; }
  else if (row < 128) { src = wk  + (row-64)*2048;  }
  else if (row < 192) { src = wv  + (row-128)*2048; }
  else if (row < 200) { src = wqa + (row-192)*2048; sc = 2.f*QSCALE; }
  else if (row < 208) { src = wka + (row-200)*2048; sc = 2.f; }
  else if (row < 216) { src = wva + (row-208)*2048; sc = 2.f; }
  for (int c = threadIdx.x; c < 2048; c += 256)
    W1[row*2048 + c] = src ? f2bf(src[c]*sc) : (u16)0;
}

// ---------- kernel 3: Weff[e][f] = wo_share[e][f] + wo[e][f%64], bf16 ----------
__global__ __launch_bounds__(256) void k_prep_weff(const float* __restrict__ wo,
    const float* __restrict__ wos, u16* __restrict__ W) {
  const int e = blockIdx.x;
  for (int f = threadIdx.x; f < 1024; f += 256)
    W[e*1024 + f] = f2bf(wos[e*1024 + f] + wo[e*64 + (f & 63)]);
}

// ---------- GEMM: C[M][N] = A[M][K] * B[N][K]^T, bf16 in / fp32 out ----------
// m97-style: linear LDS + global_load_lds(16B), 2-barrier K-loop.
// blockIdx.z = K-split slice; C advanced by z*M*N (partials summed downstream).
template<int BM, int BN>
__global__ __launch_bounds__(256)
void k_gemm_bt(const u16* __restrict__ A, const u16* __restrict__ B,
               float* __restrict__ C, int M, int N, int K, int kslice) {
  constexpr int BK = 32;
  constexpr int WM = BM/2, WN = BN/2, FM = WM/16, FN = WN/16;
  __shared__ u16 As[BM*BK];
  __shared__ u16 Bs[BN*BK];
  const int tid = threadIdx.x;
  const int w = tid >> 6, l = tid & 63;
  const int wm = (w >> 1)*WM, wn = (w & 1)*WN;
  const int tm = blockIdx.y*BM, tn = blockIdx.x*BN;
  const int k0 = blockIdx.z * kslice;
  C += (size_t)blockIdx.z * M * N;
  const int lr = l >> 2;          // row within 16-row staging chunk
  const int lk = (l & 3)*8;       // k offset within chunk
  const int la = l & 15, lko = (l >> 4)*8;

  f32x4 acc[FM][FN];
#pragma unroll
  for (int i = 0; i < FM; ++i)
#pragma unroll
    for (int j = 0; j < FN; ++j) acc[i][j] = (f32x4){0.f,0.f,0.f,0.f};

  const int nk = kslice / BK;
  for (int kt = 0; kt < nk; ++kt) {
    const int kk = k0 + kt*BK + lk;
#pragma unroll
    for (int ci = 0; ci < BM/64; ++ci) {        // A chunks, 4 waves round-robin
      const int c = w + ci*4;
      async_ld16(A + (size_t)(tm + c*16 + lr)*K + kk, &As[c*512]);
    }
#pragma unroll
    for (int ci = 0; ci < BN/64; ++ci) {        // B chunks
      const int c = w + ci*4;
      async_ld16(B + (size_t)(tn + c*16 + lr)*K + kk, &Bs[c*512]);
    }
    __syncthreads();                            // drains vmcnt before use
    short8 af[FM], bfr[FN];
#pragma unroll
    for (int mi = 0; mi < FM; ++mi)
      af[mi] = *(const short8*)&As[(wm + mi*16 + la)*BK + lko];
#pragma unroll
    for (int ni = 0; ni < FN; ++ni)
      bfr[ni] = *(const short8*)&Bs[(wn + ni*16 + la)*BK + lko];
#pragma unroll
    for (int mi = 0; mi < FM; ++mi)
#pragma unroll
      for (int ni = 0; ni < FN; ++ni)
        acc[mi][ni] = mfma16(af[mi], bfr[ni], acc[mi][ni]);
    __syncthreads();
  }
  // C/D layout: col = lane&15, row = (lane>>4)*4 + reg  [m89-verified]
#pragma unroll
  for (int mi = 0; mi < FM; ++mi)
#pragma unroll
    for (int ni = 0; ni < FN; ++ni) {
      const int r0 = tm + wm + mi*16 + (l >> 4)*4;
      const int cc = tn + wn + ni*16 + la;
#pragma unroll
      for (int r = 0; r < 4; ++r)
        C[(size_t)(r0 + r)*N + cc] = acc[mi][ni][r];
    }
}

// ---------- kernel 5: expand base+LoRA, RoPE, write Q/K/V (bf16) ----------
// proj: 4 split-K partials of [2048][256] fp32.
// cols: 0-63 base_q | 64-127 base_k | 128-191 base_v | 192-199 t_q | 200-207 t_k | 208-215 t_v
// slot 0-15: Q head  | 16-19: K kv-head | 20-23: V kv-head (V stored transposed [kh][d][t])
__global__ __launch_bounds__(64)
void k_expand(const float* __restrict__ proj, const float* __restrict__ wqb,
              const float* __restrict__ wkb, const float* __restrict__ wvb,
              const float* __restrict__ freq, u16* __restrict__ Q,
              u16* __restrict__ Kb, u16* __restrict__ Vt) {
  const int s = blockIdx.x;
  const int slot = blockIdx.y;
  const int d = threadIdx.x;
  const float* pr = proj + s*256;
  int bcol, tb; const float* wb;
  if (slot < 16)      { bcol = 0;   tb = 192; wb = wqb + (slot*64 + d)*8; }
  else if (slot < 20) { bcol = 64;  tb = 200; wb = wkb + ((slot-16)*64 + d)*8; }
  else                { bcol = 128; tb = 208; wb = wvb + ((slot-20)*64 + d)*8; }
  float base = 0.f, t[8];
#pragma unroll
  for (int r = 0; r < 8; ++r) t[r] = 0.f;
#pragma unroll
  for (int p = 0; p < 4; ++p) {
    const float* pp = pr + p*524288;
    base += pp[bcol + d];
#pragma unroll
    for (int r = 0; r < 8; ++r) t[r] += pp[tb + r];
  }
  float val = base;
#pragma unroll
  for (int r = 0; r < 8; ++r) val += t[r]*wb[r];
  if (slot < 20) {  // RoPE (Q and K)
    float partner = __shfl_xor(val, 1);
    float c  = freq[s*64 + (d >> 1)*2];
    float sn = freq[s*64 + (d >> 1)*2 + 1];
    val = (d & 1) ? (partner*sn + val*c) : (val*c - partner*sn);
  }
  u16 o = f2bf(val);
  if (slot < 16)      Q [((size_t)slot*2048 + s)*64 + d] = o;
  else if (slot < 20) Kb[((size_t)(slot-16)*2048 + s)*64 + d] = o;
  else                Vt[(size_t)(slot-20)*131072 + d*2048 + s] = o;
}

// ---------- kernel 6: causal flash attention ----------
// grid (32 q-tiles, 16 heads), 4 waves x 16 q-rows, t-tiles of 32.
__global__ __launch_bounds__(256)
void k_attn(const u16* __restrict__ Q, const u16* __restrict__ Kb,
            const u16* __restrict__ Vt, u16* __restrict__ O) {
  __shared__ u16 lds_k[32*72];      // K tile [t][d], pad 64->72
  __shared__ u16 lds_v[64*40];      // V^T tile [d][t], pad 32->40
  __shared__ u16 lds_p[4*16*40];    // per-wave P tile [q][t], pad 32->40
  const int tid = threadIdx.x;
  const int w = tid >> 6, l = tid & 63;
  const int h = blockIdx.y, kh = h >> 2;
  const int qt = blockIdx.x;
  const int q0w = qt*64 + w*16;
  const int la = l & 15, lg = l >> 4;

  const u16* Qh = Q  + (size_t)h *131072;
  const u16* Kh = Kb + (size_t)kh*131072;
  const u16* Vh = Vt + (size_t)kh*131072;

  short8 aq0 = *(const short8*)&Qh[(q0w + la)*64 + lg*8];
  short8 aq1 = *(const short8*)&Qh[(q0w + la)*64 + 32 + lg*8];

  float m[4], lsum[4];
  f32x4 o[4];
#pragma unroll
  for (int r = 0; r < 4; ++r) { m[r] = -1e30f; lsum[r] = 0.f; o[r] = (f32x4){0,0,0,0}; }

  const int st_t = tid >> 3, st_d = (tid & 7)*8;   // K staging
  const int sv_d = tid >> 2, sv_t = (tid & 3)*8;   // V staging
  const int nt = 2*(qt + 1);

  for (int tt = 0; tt < nt; ++tt) {
    const int t0 = tt*32;
    *(short8*)&lds_k[st_t*72 + st_d] = *(const short8*)&Kh[(t0 + st_t)*64 + st_d];
    *(short8*)&lds_v[sv_d*40 + sv_t] = *(const short8*)&Vh[sv_d*2048 + t0 + sv_t];
    __syncthreads();
    if (t0 <= q0w + 15) {           // wave-uniform: any unmasked element?
      f32x4 s0 = {0,0,0,0}, s1 = {0,0,0,0};
      {
        short8 b00 = *(const short8*)&lds_k[la*72 + lg*8];
        short8 b01 = *(const short8*)&lds_k[la*72 + 32 + lg*8];
        s0 = mfma16(aq0, b00, s0); s0 = mfma16(aq1, b01, s0);
        short8 b10 = *(const short8*)&lds_k[(16 + la)*72 + lg*8];
        short8 b11 = *(const short8*)&lds_k[(16 + la)*72 + 32 + lg*8];
        s1 = mfma16(aq0, b10, s1); s1 = mfma16(aq1, b11, s1);
      }
      if (t0 + 31 > q0w) {          // causal mask (log2-domain scores)
#pragma unroll
        for (int r = 0; r < 4; ++r) {
          const int qrow = q0w + lg*4 + r;
          if (t0 + la > qrow)      s0[r] = -1e30f;
          if (t0 + 16 + la > qrow) s1[r] = -1e30f;
        }
      }
#pragma unroll
      for (int r = 0; r < 4; ++r) {   // online softmax, row = q
        float mx = fmaxf(s0[r], s1[r]);
        mx = fmaxf(mx, __shfl_xor(mx, 1));
        mx = fmaxf(mx, __shfl_xor(mx, 2));
        mx = fmaxf(mx, __shfl_xor(mx, 4));
        mx = fmaxf(mx, __shfl_xor(mx, 8));
        const float mnew = fmaxf(m[r], mx);
        const float al = exp2f(m[r] - mnew);
        const float p0 = exp2f(s0[r] - mnew);
        const float p1 = exp2f(s1[r] - mnew);
        float rs = p0 + p1;
        rs += __shfl_xor(rs, 1);
        rs += __shfl_xor(rs, 2);
        rs += __shfl_xor(rs, 4);
        rs += __shfl_xor(rs, 8);
        lsum[r] = lsum[r]*al + rs;
        m[r] = mnew;
        o[0][r] *= al; o[1][r] *= al; o[2][r] *= al; o[3][r] *= al;
        lds_p[(w*16 + lg*4 + r)*40 + la]      = f2bf(p0);
        lds_p[(w*16 + lg*4 + r)*40 + 16 + la] = f2bf(p1);
      }
      short8 ap = *(const short8*)&lds_p[(w*16 + la)*40 + lg*8];
#pragma unroll
      for (int nb = 0; nb < 4; ++nb) {
        short8 bv = *(const short8*)&lds_v[(nb*16 + la)*40 + lg*8];
        o[nb] = mfma16(ap, bv, o[nb]);
      }
    }
    __syncthreads();
  }
#pragma unroll
  for (int r = 0; r < 4; ++r) lsum[r] = 1.f/lsum[r];
#pragma unroll
  for (int nb = 0; nb < 4; ++nb)
#pragma unroll
    for (int r = 0; r < 4; ++r)
      O[(size_t)(q0w + lg*4 + r)*1024 + h*64 + nb*16 + la] = f2bf(o[nb][r]*lsum[r]);
}

// ---------- launch ----------
extern "C" void kernel_launch(void* const* d_in, const int* in_sizes, int n_in,
                              void* d_out, int out_size, void* d_ws, size_t ws_size,
                              hipStream_t stream) {
  const float* x    = (const float*)d_in[0];
  const float* freq = (const float*)d_in[1];
  const float* wq   = (const float*)d_in[2];
  const float* wqa  = (const float*)d_in[3];
  const float* wqb  = (const float*)d_in[4];
  const float* wk   = (const float*)d_in[5];
  const float* wka  = (const float*)d_in[6];
  const float* wkb  = (const float*)d_in[7];
  const float* wv   = (const float*)d_in[8];
  const float* wva  = (const float*)d_in[9];
  const float* wvb  = (const float*)d_in[10];
  const float* wo   = (const float*)d_in[11];
  const float* wos  = (const float*)d_in[12];
  float* out = (float*)d_out;

  char* ws = (char*)d_ws;
  // region 0 (8MB): x_bf, later reused for Q/K/Vt (stream-ordered, safe)
  u16*  x_bf = (u16*)ws;
  u16*  Qb   = (u16*)ws;                  // 4MB  (written after x_bf is dead)
  u16*  Kbuf = (u16*)(ws + (4u<<20));     // 1MB
  u16*  Vtb  = (u16*)(ws + (5u<<20));     // 1MB
  u16*  W1   = (u16*)(ws + (8u<<20));     // 1MB
  u16*  Weff = (u16*)(ws + (9u<<20));     // 4MB
  // region (13MB..21MB): proj partials, later reused for O_bf
  float* proj = (float*)(ws + (13u<<20)); // 8MB (4 x [2048][256] fp32)
  u16*  Obf  = (u16*)(ws + (13u<<20));    // 4MB  (written after proj is dead)

  k_conv_x  <<<1024, 256, 0, stream>>>(x, x_bf, 1048576);
  k_prep_w1 <<<256,  256, 0, stream>>>(wq, wk, wv, wqa, wka, wva, W1);
  k_prep_weff<<<2048, 256, 0, stream>>>(wo, wos, Weff);
  // stage A: proj = x_bf @ W1^T   (M=2048, N=256, K=2048, split-K=4 -> 256 blocks)
  k_gemm_bt<128,64><<<dim3(4,16,4), 256, 0, stream>>>(x_bf, W1, proj, 2048, 256, 2048, 512);
  k_expand  <<<dim3(2048,24), 64, 0, stream>>>(proj, wqb, wkb, wvb, freq, Qb, Kbuf, Vtb);
  k_attn    <<<dim3(32,16), 256, 0, stream>>>(Qb, Kbuf, Vtb, Obf);
  // stage D: out = Obf @ Weff^T   (M=2048, N=2048, K=1024 -> 256 blocks)
  k_gemm_bt<128,128><<<dim3(16,16,1), 256, 0, stream>>>(Obf, Weff, out, 2048, 2048, 1024, 1024);
}

// Round 2
// 151.185 us; speedup vs baseline: 1.3863x; 1.3863x over previous
//
#include <hip/hip_runtime.h>
#include <hip/hip_bf16.h>

#define DEV __device__ __forceinline__

typedef unsigned short u16;
typedef __attribute__((ext_vector_type(8))) short short8;  // 8 bf16 (4 VGPRs)
typedef __attribute__((ext_vector_type(4))) float f32x4;   // MFMA C/D

// ---------- helpers ----------
DEV u16 f2bf(float f) {               // RNE float -> bf16 bits
  union { float f; unsigned u; } v; v.f = f;
  unsigned r = v.u + 0x7FFFu + ((v.u >> 16) & 1u);
  return (u16)(r >> 16);
}

DEV void async_ld16(const u16* g, u16* l) {
  // global -> LDS direct, 16B per lane; LDS dest = wave-uniform base (+lane*16 implicit)
  __builtin_amdgcn_global_load_lds((__attribute__((address_space(1))) void*)g,
                                   (__attribute__((address_space(3))) void*)l,
                                   16, 0, 0);
}

DEV f32x4 mfma16(short8 a, short8 b, f32x4 c) {
  return __builtin_amdgcn_mfma_f32_16x16x32_bf16(a, b, c, 0, 0, 0);
}

// ---------- constants ----------
// scores use exp2: fold 1/sqrt(64) * log2(e) into Q path; LORA_SCALE=2 into w_a rows
#define QSCALE (0.125f * 1.4426950408889634f)

// ---------- kernel 1: x fp32 -> bf16 ----------
__global__ __launch_bounds__(256) void k_conv_x(const float* __restrict__ x,
                                                u16* __restrict__ xb, int n4) {
  int i = blockIdx.x * 256 + threadIdx.x;
  int stride = gridDim.x * 256;
  for (; i < n4; i += stride) {
    float4 v = ((const float4*)x)[i];
    ushort4 o;
    o.x = f2bf(v.x); o.y = f2bf(v.y); o.z = f2bf(v.z); o.w = f2bf(v.w);
    ((ushort4*)xb)[i] = o;
  }
}

// ---------- kernel 2: combined projection weight W1 [256][2048] bf16 ----------
__global__ __launch_bounds__(256) void k_prep_w1(const float* __restrict__ wq,
    const float* __restrict__ wk, const float* __restrict__ wv,
    const float* __restrict__ wqa, const float* __restrict__ wka,
    const float* __restrict__ wva, u16* __restrict__ W1) {
  const int row = blockIdx.x;
  const float* src = nullptr; float sc = 1.f;
  if (row < 64)       { src = wq  + row*2048;       sc = QSCALE; }
  else if (row < 128) { src = wk  + (row-64)*2048;  }
  else if (row < 192) { src = wv  + (row-128)*2048; }
  else if (row < 200) { src = wqa + (row-192)*2048; sc = 2.f*QSCALE; }
  else if (row < 208) { src = wka + (row-200)*2048; sc = 2.f; }
  else if (row < 216) { src = wva + (row-208)*2048; sc = 2.f; }
  for (int c = threadIdx.x; c < 2048; c += 256)
    W1[row*2048 + c] = src ? f2bf(src[c]*sc) : (u16)0;
}

// ---------- kernel 3: Weff[e][f] = wo_share[e][f] + wo[e][f%64], bf16 ----------
__global__ __launch_bounds__(256) void k_prep_weff(const float* __restrict__ wo,
    const float* __restrict__ wos, u16* __restrict__ W) {
  const int e = blockIdx.x;
  for (int f = threadIdx.x; f < 1024; f += 256)
    W[e*1024 + f] = f2bf(wos[e*1024 + f] + wo[e*64 + (f & 63)]);
}

// ---------- GEMM: C[M][N] = A[M][K] * B[N][K]^T, bf16 in / fp32 out ----------
template<int BM, int BN>
__global__ __launch_bounds__(256)
void k_gemm_bt(const u16* __restrict__ A, const u16* __restrict__ B,
               float* __restrict__ C, int M, int N, int K, int kslice) {
  constexpr int BK = 32;
  constexpr int WM = BM/2, WN = BN/2, FM = WM/16, FN = WN/16;
  __shared__ u16 As[BM*BK];
  __shared__ u16 Bs[BN*BK];
  const int tid = threadIdx.x;
  const int w = tid >> 6, l = tid & 63;
  const int wm = (w >> 1)*WM, wn = (w & 1)*WN;
  const int tm = blockIdx.y*BM, tn = blockIdx.x*BN;
  const int k0 = blockIdx.z * kslice;
  C += (size_t)blockIdx.z * M * N;
  const int lr = l >> 2;
  const int lk = (l & 3)*8;
  const int la = l & 15, lko = (l >> 4)*8;

  f32x4 acc[FM][FN];
#pragma unroll
  for (int i = 0; i < FM; ++i)
#pragma unroll
    for (int j = 0; j < FN; ++j) acc[i][j] = (f32x4){0.f,0.f,0.f,0.f};

  const int nk = kslice / BK;
  for (int kt = 0; kt < nk; ++kt) {
    const int kk = k0 + kt*BK + lk;
#pragma unroll
    for (int ci = 0; ci < BM/64; ++ci) {
      const int c = w + ci*4;
      async_ld16(A + (size_t)(tm + c*16 + lr)*K + kk, &As[c*512]);
    }
#pragma unroll
    for (int ci = 0; ci < BN/64; ++ci) {
      const int c = w + ci*4;
      async_ld16(B + (size_t)(tn + c*16 + lr)*K + kk, &Bs[c*512]);
    }
    __syncthreads();
    short8 af[FM], bfr[FN];
#pragma unroll
    for (int mi = 0; mi < FM; ++mi)
      af[mi] = *(const short8*)&As[(wm + mi*16 + la)*BK + lko];
#pragma unroll
    for (int ni = 0; ni < FN; ++ni)
      bfr[ni] = *(const short8*)&Bs[(wn + ni*16 + la)*BK + lko];
#pragma unroll
    for (int mi = 0; mi < FM; ++mi)
#pragma unroll
      for (int ni = 0; ni < FN; ++ni)
        acc[mi][ni] = mfma16(af[mi], bfr[ni], acc[mi][ni]);
    __syncthreads();
  }
#pragma unroll
  for (int mi = 0; mi < FM; ++mi)
#pragma unroll
    for (int ni = 0; ni < FN; ++ni) {
      const int r0 = tm + wm + mi*16 + (l >> 4)*4;
      const int cc = tn + wn + ni*16 + la;
#pragma unroll
      for (int r = 0; r < 4; ++r)
        C[(size_t)(r0 + r)*N + cc] = acc[mi][ni][r];
    }
}

// ---------- kernel 5: expand base+LoRA, RoPE, write Q/K/V (bf16) ----------
__global__ __launch_bounds__(64)
void k_expand(const float* __restrict__ proj, const float* __restrict__ wqb,
              const float* __restrict__ wkb, const float* __restrict__ wvb,
              const float* __restrict__ freq, u16* __restrict__ Q,
              u16* __restrict__ Kb, u16* __restrict__ Vt) {
  const int s = blockIdx.x;
  const int slot = blockIdx.y;
  const int d = threadIdx.x;
  const float* pr = proj + s*256;
  int bcol, tb; const float* wb;
  if (slot < 16)      { bcol = 0;   tb = 192; wb = wqb + (slot*64 + d)*8; }
  else if (slot < 20) { bcol = 64;  tb = 200; wb = wkb + ((slot-16)*64 + d)*8; }
  else                { bcol = 128; tb = 208; wb = wvb + ((slot-20)*64 + d)*8; }
  float base = 0.f, t[8];
#pragma unroll
  for (int r = 0; r < 8; ++r) t[r] = 0.f;
#pragma unroll
  for (int p = 0; p < 4; ++p) {
    const float* pp = pr + p*524288;
    base += pp[bcol + d];
#pragma unroll
    for (int r = 0; r < 8; ++r) t[r] += pp[tb + r];
  }
  float val = base;
#pragma unroll
  for (int r = 0; r < 8; ++r) val += t[r]*wb[r];
  if (slot < 20) {  // RoPE (Q and K)
    float partner = __shfl_xor(val, 1);
    float c  = freq[s*64 + (d >> 1)*2];
    float sn = freq[s*64 + (d >> 1)*2 + 1];
    val = (d & 1) ? (partner*sn + val*c) : (val*c - partner*sn);
  }
  u16 o = f2bf(val);
  if (slot < 16)      Q [((size_t)slot*2048 + s)*64 + d] = o;
  else if (slot < 20) Kb[((size_t)(slot-16)*2048 + s)*64 + d] = o;
  else                Vt[(size_t)(slot-20)*131072 + d*2048 + s] = o;
}

// ---------- kernel 6: causal flash attention (v2) ----------
// t-tile 64, double-buffered global_load_lds staging (stage-early / 1 barrier),
// XOR-swizzled LDS (inverse-swizzled global source), ILP'd online softmax.
// grid (32 q-tiles, 16 heads), 4 waves x 16 q-rows.
__global__ __launch_bounds__(256)
void k_attn(const u16* __restrict__ Q, const u16* __restrict__ Kb,
            const u16* __restrict__ Vt, u16* __restrict__ O) {
  __shared__ u16 kbuf[2][64*64];    // K tile [t][d], swizzled
  __shared__ u16 vbuf[2][64*64];    // V^T tile [d][t], swizzled
  __shared__ u16 pbuf[4][16*64];    // per-wave P tile [q][t], swizzled
  const int tid = threadIdx.x;
  const int w = tid >> 6, l = tid & 63;
  const int h = blockIdx.y, kh = h >> 2;
  const int qt = blockIdx.x;
  const int q0w = qt*64 + w*16;
  const int la = l & 15, lg = l >> 4;
  const int swz = (la & 7) << 3;    // read-side XOR (u16 units)

  const u16* Qh = Q  + (size_t)h *131072;
  const u16* Kh = Kb + (size_t)kh*131072;
  const u16* Vh = Vt + (size_t)kh*131072;

  short8 aq0 = *(const short8*)&Qh[(q0w + la)*64 + lg*8];
  short8 aq1 = *(const short8*)&Qh[(q0w + la)*64 + 32 + lg*8];

  float m[4], lsum[4];
  f32x4 o[4];
#pragma unroll
  for (int r = 0; r < 4; ++r) { m[r] = -1e30f; lsum[r] = 0.f; o[r] = (f32x4){0,0,0,0}; }

  // staging chunk geometry: chunk c = w*128 + j*64 + l; row=c>>3; src col inverse-swizzled
  const int c0 = w*128 + l, c1 = c0 + 64;
  const int kr0 = c0 >> 3, kr1 = c1 >> 3;                 // tile rows this lane fetches
  const int kc0 = ((c0 & 7) ^ (kr0 & 7))*8;               // inverse-swizzled col (u16)
  const int kc1 = ((c1 & 7) ^ (kr1 & 7))*8;

  const int nt = qt + 1;
  int cur = 0;

  // prologue: stage tile 0 into buf 0
  {
    async_ld16(Kh + (size_t)kr0*64 + kc0, &kbuf[0][w*1024]);
    async_ld16(Kh + (size_t)kr1*64 + kc1, &kbuf[0][w*1024 + 512]);
    async_ld16(Vh + (size_t)kr0*2048 + kc0, &vbuf[0][w*1024]);
    async_ld16(Vh + (size_t)kr1*2048 + kc1, &vbuf[0][w*1024 + 512]);
  }
  __syncthreads();

  for (int tt = 0; tt < nt; ++tt) {
    const int t0 = tt*64;
    if (tt + 1 < nt) {                      // prefetch next tile (other buffer)
      const int tn0 = t0 + 64;
      const int nb_ = cur ^ 1;
      async_ld16(Kh + (size_t)(tn0 + kr0)*64 + kc0, &kbuf[nb_][w*1024]);
      async_ld16(Kh + (size_t)(tn0 + kr1)*64 + kc1, &kbuf[nb_][w*1024 + 512]);
      async_ld16(Vh + (size_t)kr0*2048 + tn0 + kc0, &vbuf[nb_][w*1024]);
      async_ld16(Vh + (size_t)kr1*2048 + tn0 + kc1, &vbuf[nb_][w*1024 + 512]);
    }

    // ---- QK^T: 4 t-blocks x 2 k-halves ----
    f32x4 s[4];
#pragma unroll
    for (int tb = 0; tb < 4; ++tb) {
      s[tb] = (f32x4){0,0,0,0};
      const int row = tb*16 + la;
      short8 b0 = *(const short8*)&kbuf[cur][(row*64 + lg*8) ^ swz];
      short8 b1 = *(const short8*)&kbuf[cur][(row*64 + 32 + lg*8) ^ swz];
      s[tb] = mfma16(aq0, b0, s[tb]);
      s[tb] = mfma16(aq1, b1, s[tb]);
    }

    if (tt == nt - 1) {                     // causal mask (diagonal tile only)
#pragma unroll
      for (int r = 0; r < 4; ++r) {
        const int qrow = q0w + lg*4 + r;
#pragma unroll
        for (int tb = 0; tb < 4; ++tb)
          if (t0 + tb*16 + la > qrow) s[tb][r] = -1e30f;
      }
    }

    // ---- online softmax: 4 independent row chains ----
#pragma unroll
    for (int r = 0; r < 4; ++r) {
      float mx = fmaxf(fmaxf(s[0][r], s[1][r]), fmaxf(s[2][r], s[3][r]));
      mx = fmaxf(mx, __shfl_xor(mx, 1));
      mx = fmaxf(mx, __shfl_xor(mx, 2));
      mx = fmaxf(mx, __shfl_xor(mx, 4));
      mx = fmaxf(mx, __shfl_xor(mx, 8));
      const float mnew = fmaxf(m[r], mx);
      const float al = exp2f(m[r] - mnew);
      const float p0 = exp2f(s[0][r] - mnew);
      const float p1 = exp2f(s[1][r] - mnew);
      const float p2 = exp2f(s[2][r] - mnew);
      const float p3 = exp2f(s[3][r] - mnew);
      float rs = (p0 + p1) + (p2 + p3);
      rs += __shfl_xor(rs, 1);
      rs += __shfl_xor(rs, 2);
      rs += __shfl_xor(rs, 4);
      rs += __shfl_xor(rs, 8);
      lsum[r] = lsum[r]*al + rs;
      m[r] = mnew;
      o[0][r] *= al; o[1][r] *= al; o[2][r] *= al; o[3][r] *= al;
      const int prow = lg*4 + r;
      const int psw = (prow & 7) << 3;
      pbuf[w][(prow*64 +      la) ^ psw] = f2bf(p0);
      pbuf[w][(prow*64 + 16 + la) ^ psw] = f2bf(p1);
      pbuf[w][(prow*64 + 32 + la) ^ psw] = f2bf(p2);
      pbuf[w][(prow*64 + 48 + la) ^ psw] = f2bf(p3);
    }

    // ---- PV: P [16q x 64t] @ V^T, k = t (2 k-steps) ----
    short8 ap0 = *(const short8*)&pbuf[w][(la*64 +      lg*8) ^ swz];
    short8 ap1 = *(const short8*)&pbuf[w][(la*64 + 32 + lg*8) ^ swz];
#pragma unroll
    for (int nb = 0; nb < 4; ++nb) {
      const int vr = nb*16 + la;
      short8 bv0 = *(const short8*)&vbuf[cur][(vr*64 +      lg*8) ^ swz];
      short8 bv1 = *(const short8*)&vbuf[cur][(vr*64 + 32 + lg*8) ^ swz];
      o[nb] = mfma16(ap0, bv0, o[nb]);
      o[nb] = mfma16(ap1, bv1, o[nb]);
    }

    __syncthreads();    // drains prefetch vmcnt; next buffer ready; LDS reuse safe
    cur ^= 1;
  }

#pragma unroll
  for (int r = 0; r < 4; ++r) lsum[r] = 1.f/lsum[r];
#pragma unroll
  for (int nb = 0; nb < 4; ++nb)
#pragma unroll
    for (int r = 0; r < 4; ++r)
      O[(size_t)(q0w + lg*4 + r)*1024 + h*64 + nb*16 + la] = f2bf(o[nb][r]*lsum[r]);
}

// ---------- launch ----------
extern "C" void kernel_launch(void* const* d_in, const int* in_sizes, int n_in,
                              void* d_out, int out_size, void* d_ws, size_t ws_size,
                              hipStream_t stream) {
  const float* x    = (const float*)d_in[0];
  const float* freq = (const float*)d_in[1];
  const float* wq   = (const float*)d_in[2];
  const float* wqa  = (const float*)d_in[3];
  const float* wqb  = (const float*)d_in[4];
  const float* wk   = (const float*)d_in[5];
  const float* wka  = (const float*)d_in[6];
  const float* wkb  = (const float*)d_in[7];
  const float* wv   = (const float*)d_in[8];
  const float* wva  = (const float*)d_in[9];
  const float* wvb  = (const float*)d_in[10];
  const float* wo   = (const float*)d_in[11];
  const float* wos  = (const float*)d_in[12];
  float* out = (float*)d_out;

  char* ws = (char*)d_ws;
  u16*  x_bf = (u16*)ws;
  u16*  Qb   = (u16*)ws;                  // reuses x_bf region (stream-ordered)
  u16*  Kbuf = (u16*)(ws + (4u<<20));
  u16*  Vtb  = (u16*)(ws + (5u<<20));
  u16*  W1   = (u16*)(ws + (8u<<20));
  u16*  Weff = (u16*)(ws + (9u<<20));
  float* proj = (float*)(ws + (13u<<20));
  u16*  Obf  = (u16*)(ws + (13u<<20));    // reuses proj region

  k_conv_x  <<<1024, 256, 0, stream>>>(x, x_bf, 1048576);
  k_prep_w1 <<<256,  256, 0, stream>>>(wq, wk, wv, wqa, wka, wva, W1);
  k_prep_weff<<<2048, 256, 0, stream>>>(wo, wos, Weff);
  k_gemm_bt<128,64><<<dim3(4,16,4), 256, 0, stream>>>(x_bf, W1, proj, 2048, 256, 2048, 512);
  k_expand  <<<dim3(2048,24), 64, 0, stream>>>(proj, wqb, wkb, wvb, freq, Qb, Kbuf, Vtb);
  k_attn    <<<dim3(32,16), 256, 0, stream>>>(Qb, Kbuf, Vtb, Obf);
  k_gemm_bt<128,128><<<dim3(16,16,1), 256, 0, stream>>>(Obf, Weff, out, 2048, 2048, 1024, 1024);
}

// Round 3
// 135.020 us; speedup vs baseline: 1.5522x; 1.1197x over previous
//
#include <hip/hip_runtime.h>
#include <hip/hip_bf16.h>

#define DEV __device__ __forceinline__

typedef unsigned short u16;
typedef __attribute__((ext_vector_type(8))) short short8;   // 8 bf16 (4 VGPRs)
typedef __attribute__((ext_vector_type(4))) float f32x4;    // 16x16 MFMA C/D
typedef __attribute__((ext_vector_type(16))) float f32x16;  // 32x32 MFMA C/D

// ---------- helpers ----------
DEV u16 f2bf(float f) {               // RNE float -> bf16 bits
  union { float f; unsigned u; } v; v.f = f;
  unsigned r = v.u + 0x7FFFu + ((v.u >> 16) & 1u);
  return (u16)(r >> 16);
}

DEV unsigned cvtpk(float lo, float hi) {  // packed bf16x2 (RNE)
  unsigned r;
  asm("v_cvt_pk_bf16_f32 %0, %1, %2" : "=v"(r) : "v"(lo), "v"(hi));
  return r;
}

DEV void async_ld16(const u16* g, u16* l) {
  __builtin_amdgcn_global_load_lds((__attribute__((address_space(1))) void*)g,
                                   (__attribute__((address_space(3))) void*)l,
                                   16, 0, 0);
}

DEV f32x4 mfma16(short8 a, short8 b, f32x4 c) {
  return __builtin_amdgcn_mfma_f32_16x16x32_bf16(a, b, c, 0, 0, 0);
}
DEV f32x16 mfma32(short8 a, short8 b, f32x16 c) {
  return __builtin_amdgcn_mfma_f32_32x32x16_bf16(a, b, c, 0, 0, 0);
}

DEV short8 mkfrag(unsigned w0, unsigned w1, unsigned w2, unsigned w3) {
  union { unsigned u[4]; short8 s; } u;
  u.u[0] = w0; u.u[1] = w1; u.u[2] = w2; u.u[3] = w3;
  return u.s;
}

// swizzled LDS b128 read from a [rows][64] bf16 tile (128B rows)
DEV short8 lds_rd(const u16* buf, int row, int colb) {
  return *(const short8*)((const char*)buf + row*128 + (colb ^ ((row & 7) << 4)));
}

#define QSCALE (0.125f * 1.4426950408889634f)

// ---------- kernel 1: fused prep (x->bf16 | W1 | Weff) ----------
__global__ __launch_bounds__(256) void k_prep(const float* __restrict__ x,
    const float* __restrict__ wq, const float* __restrict__ wk,
    const float* __restrict__ wv, const float* __restrict__ wqa,
    const float* __restrict__ wka, const float* __restrict__ wva,
    const float* __restrict__ wo, const float* __restrict__ wos,
    u16* __restrict__ xb, u16* __restrict__ W1, u16* __restrict__ Weff) {
  const int bid = blockIdx.x;
  if (bid < 1024) {                     // x fp32 -> bf16 (1048576 float4)
    int i = bid*256 + threadIdx.x;
    for (; i < 1048576; i += 1024*256) {
      float4 v = ((const float4*)x)[i];
      ushort4 o;
      o.x = f2bf(v.x); o.y = f2bf(v.y); o.z = f2bf(v.z); o.w = f2bf(v.w);
      ((ushort4*)xb)[i] = o;
    }
  } else if (bid < 1280) {              // W1 row
    const int row = bid - 1024;
    const float* src = nullptr; float sc = 1.f;
    if (row < 64)       { src = wq  + row*2048;       sc = QSCALE; }
    else if (row < 128) { src = wk  + (row-64)*2048;  }
    else if (row < 192) { src = wv  + (row-128)*2048; }
    else if (row < 200) { src = wqa + (row-192)*2048; sc = 2.f*QSCALE; }
    else if (row < 208) { src = wka + (row-200)*2048; sc = 2.f; }
    else if (row < 216) { src = wva + (row-208)*2048; sc = 2.f; }
    for (int c = threadIdx.x; c < 2048; c += 256)
      W1[row*2048 + c] = src ? f2bf(src[c]*sc) : (u16)0;
  } else {                              // Weff row
    const int e = bid - 1280;
    for (int f = threadIdx.x; f < 1024; f += 256)
      Weff[e*1024 + f] = f2bf(wos[e*1024 + f] + wo[e*64 + (f & 63)]);
  }
}

// ---------- GEMM: C[M][N] = A[M][K] * B[N][K]^T, bf16 in / fp32 out ----------
template<int BM, int BN>
__global__ __launch_bounds__(256)
void k_gemm_bt(const u16* __restrict__ A, const u16* __restrict__ B,
               float* __restrict__ C, int M, int N, int K, int kslice) {
  constexpr int BK = 32;
  constexpr int WM = BM/2, WN = BN/2, FM = WM/16, FN = WN/16;
  __shared__ u16 As[BM*BK];
  __shared__ u16 Bs[BN*BK];
  const int tid = threadIdx.x;
  const int w = tid >> 6, l = tid & 63;
  const int wm = (w >> 1)*WM, wn = (w & 1)*WN;
  const int tm = blockIdx.y*BM, tn = blockIdx.x*BN;
  const int k0 = blockIdx.z * kslice;
  C += (size_t)blockIdx.z * M * N;
  const int lr = l >> 2;
  const int lk = (l & 3)*8;
  const int la = l & 15, lko = (l >> 4)*8;

  f32x4 acc[FM][FN];
#pragma unroll
  for (int i = 0; i < FM; ++i)
#pragma unroll
    for (int j = 0; j < FN; ++j) acc[i][j] = (f32x4){0.f,0.f,0.f,0.f};

  const int nk = kslice / BK;
  for (int kt = 0; kt < nk; ++kt) {
    const int kk = k0 + kt*BK + lk;
#pragma unroll
    for (int ci = 0; ci < BM/64; ++ci) {
      const int c = w + ci*4;
      async_ld16(A + (size_t)(tm + c*16 + lr)*K + kk, &As[c*512]);
    }
#pragma unroll
    for (int ci = 0; ci < BN/64; ++ci) {
      const int c = w + ci*4;
      async_ld16(B + (size_t)(tn + c*16 + lr)*K + kk, &Bs[c*512]);
    }
    __syncthreads();
    short8 af[FM], bfr[FN];
#pragma unroll
    for (int mi = 0; mi < FM; ++mi)
      af[mi] = *(const short8*)&As[(wm + mi*16 + la)*BK + lko];
#pragma unroll
    for (int ni = 0; ni < FN; ++ni)
      bfr[ni] = *(const short8*)&Bs[(wn + ni*16 + la)*BK + lko];
#pragma unroll
    for (int mi = 0; mi < FM; ++mi)
#pragma unroll
      for (int ni = 0; ni < FN; ++ni)
        acc[mi][ni] = mfma16(af[mi], bfr[ni], acc[mi][ni]);
    __syncthreads();
  }
#pragma unroll
  for (int mi = 0; mi < FM; ++mi)
#pragma unroll
    for (int ni = 0; ni < FN; ++ni) {
      const int r0 = tm + wm + mi*16 + (l >> 4)*4;
      const int cc = tn + wn + ni*16 + la;
#pragma unroll
      for (int r = 0; r < 4; ++r)
        C[(size_t)(r0 + r)*N + cc] = acc[mi][ni][r];
    }
}

// ---------- kernel: expand base+LoRA, RoPE, write Q/K/V (bf16) ----------
__global__ __launch_bounds__(64)
void k_expand(const float* __restrict__ proj, const float* __restrict__ wqb,
              const float* __restrict__ wkb, const float* __restrict__ wvb,
              const float* __restrict__ freq, u16* __restrict__ Q,
              u16* __restrict__ Kb, u16* __restrict__ Vt) {
  const int s = blockIdx.x;
  const int slot = blockIdx.y;
  const int d = threadIdx.x;
  const float* pr = proj + s*256;
  int bcol, tb; const float* wb;
  if (slot < 16)      { bcol = 0;   tb = 192; wb = wqb + (slot*64 + d)*8; }
  else if (slot < 20) { bcol = 64;  tb = 200; wb = wkb + ((slot-16)*64 + d)*8; }
  else                { bcol = 128; tb = 208; wb = wvb + ((slot-20)*64 + d)*8; }
  float base = 0.f, t[8];
#pragma unroll
  for (int r = 0; r < 8; ++r) t[r] = 0.f;
#pragma unroll
  for (int p = 0; p < 4; ++p) {
    const float* pp = pr + p*524288;
    base += pp[bcol + d];
#pragma unroll
    for (int r = 0; r < 8; ++r) t[r] += pp[tb + r];
  }
  float val = base;
#pragma unroll
  for (int r = 0; r < 8; ++r) val += t[r]*wb[r];
  if (slot < 20) {  // RoPE (Q and K)
    float partner = __shfl_xor(val, 1);
    float c  = freq[s*64 + (d >> 1)*2];
    float sn = freq[s*64 + (d >> 1)*2 + 1];
    val = (d & 1) ? (partner*sn + val*c) : (val*c - partner*sn);
  }
  u16 o = f2bf(val);
  if (slot < 16)      Q [((size_t)slot*2048 + s)*64 + d] = o;
  else if (slot < 20) Kb[((size_t)(slot-16)*2048 + s)*64 + d] = o;
  else                Vt[(size_t)(slot-20)*131072 + d*2048 + s] = o;
}

// ---------- kernel: causal flash attention (v3: 32x32 swapped, reg softmax) ----------
// grid (16 qt, 16 h); 4 waves x 32 q-rows = 128 q/block; t-tile 64.
__global__ __launch_bounds__(256)
void k_attn(const u16* __restrict__ Q, const u16* __restrict__ Kb,
            const u16* __restrict__ Vt, u16* __restrict__ O) {
  __shared__ u16 kbuf[2][64*64];    // K tile [t][d], byte^((t&7)<<4) swizzled
  __shared__ u16 vbuf[2][64*64];    // V^T tile [d][t], same swizzle
  const int tid = threadIdx.x;
  const int w = tid >> 6, l = tid & 63;
  const int h = blockIdx.y, kh = h >> 2;
  const int qt = blockIdx.x;
  const int q0 = qt*128 + w*32;
  const int lq = l & 31, hh = l >> 5;
  const int qg = q0 + lq;

  const u16* Qh = Q  + (size_t)h *131072;
  const u16* Kh = Kb + (size_t)kh*131072;
  const u16* Vh = Vt + (size_t)kh*131072;

  // Q as B-fragments: lane holds row q=lq, k-slot hh*8, 4 k-steps of 16
  short8 bq[4];
#pragma unroll
  for (int ks = 0; ks < 4; ++ks)
    bq[ks] = *(const short8*)&Qh[qg*64 + ks*16 + hh*8];

  f32x16 acc0, acc1;                // O^T [d][q]: dt=0 -> d 0..31, dt=1 -> 32..63
#pragma unroll
  for (int r = 0; r < 16; ++r) { acc0[r] = 0.f; acc1[r] = 0.f; }
  float m = -1e30f, lsum = 0.f;

  // staging geometry (chunk c covers LDS bytes c*16; row=c>>3, inverse-swizzled src col)
  const int c0 = w*128 + l, c1 = c0 + 64;
  const int kr0 = c0 >> 3, kr1 = c1 >> 3;
  const int kc0 = ((c0 & 7) ^ (kr0 & 7))*8;
  const int kc1 = ((c1 & 7) ^ (kr1 & 7))*8;

  const int nt = 2*(qt + 1);
  int cur = 0;

  async_ld16(Kh + (size_t)kr0*64 + kc0, &kbuf[0][w*1024]);
  async_ld16(Kh + (size_t)kr1*64 + kc1, &kbuf[0][w*1024 + 512]);
  async_ld16(Vh + (size_t)kr0*2048 + kc0, &vbuf[0][w*1024]);
  async_ld16(Vh + (size_t)kr1*2048 + kc1, &vbuf[0][w*1024 + 512]);
  __syncthreads();

  for (int tt = 0; tt < nt; ++tt) {
    const int t0 = tt*64;
    if (tt + 1 < nt) {
      const int tn0 = t0 + 64;
      const int nb = cur ^ 1;
      async_ld16(Kh + (size_t)(tn0 + kr0)*64 + kc0, &kbuf[nb][w*1024]);
      async_ld16(Kh + (size_t)(tn0 + kr1)*64 + kc1, &kbuf[nb][w*1024 + 512]);
      async_ld16(Vh + (size_t)kr0*2048 + tn0 + kc0, &vbuf[nb][w*1024]);
      async_ld16(Vh + (size_t)kr1*2048 + tn0 + kc1, &vbuf[nb][w*1024 + 512]);
    }

    if (t0 <= q0 + 31) {            // wave has unmasked area (t0 <= qg for all lanes)
      // ---- QK^T swapped: S^T[t][q] = mfma(K rows, Q rows) ----
      f32x16 s0, s1;
#pragma unroll
      for (int r = 0; r < 16; ++r) { s0[r] = 0.f; s1[r] = 0.f; }
#pragma unroll
      for (int ks = 0; ks < 4; ++ks) {
        short8 ak0 = lds_rd(kbuf[cur], lq,      ks*32 + hh*16);
        short8 ak1 = lds_rd(kbuf[cur], 32 + lq, ks*32 + hh*16);
        s0 = mfma32(ak0, bq[ks], s0);
        s1 = mfma32(ak1, bq[ks], s1);
      }
      // ---- causal mask: t_glob > qg -> -inf ----
      if (t0 + 63 > q0) {
#pragma unroll
        for (int r = 0; r < 16; ++r) {
          const int tl = (r & 3) + ((r >> 2) << 3) + (hh << 2);
          if (t0 + tl > qg)      s0[r] = -1e30f;
          if (t0 + 32 + tl > qg) s1[r] = -1e30f;
        }
      }
      // ---- in-register max over 32 t (lane q) + one cross-half exchange ----
      float mx8[8];
#pragma unroll
      for (int r = 0; r < 8; ++r)
        mx8[r] = fmaxf(fmaxf(s0[r], s0[r+8]), fmaxf(s1[r], s1[r+8]));
      float mx = fmaxf(fmaxf(fmaxf(mx8[0], mx8[1]), fmaxf(mx8[2], mx8[3])),
                       fmaxf(fmaxf(mx8[4], mx8[5]), fmaxf(mx8[6], mx8[7])));
      mx = fmaxf(mx, __shfl_xor(mx, 32));
      const float mnew = fmaxf(m, mx);
      const float al = exp2f(m - mnew);
      m = mnew;
#pragma unroll
      for (int r = 0; r < 16; ++r) { acc0[r] *= al; acc1[r] *= al; }
      lsum *= al;

      // ---- P = exp2(S - m), packed bf16x2, in-register redistribution ----
      unsigned cwa[4][2], cwb[4][2];
      float psum = 0.f;
#pragma unroll
      for (int rq = 0; rq < 4; ++rq) {
        float a0 = exp2f(s0[4*rq+0] - mnew), a1 = exp2f(s0[4*rq+1] - mnew);
        float a2 = exp2f(s0[4*rq+2] - mnew), a3 = exp2f(s0[4*rq+3] - mnew);
        float b0 = exp2f(s1[4*rq+0] - mnew), b1 = exp2f(s1[4*rq+1] - mnew);
        float b2 = exp2f(s1[4*rq+2] - mnew), b3 = exp2f(s1[4*rq+3] - mnew);
        psum += (a0+a1) + (a2+a3) + (b0+b1) + (b2+b3);
        cwa[rq][0] = cvtpk(a0, a1); cwa[rq][1] = cvtpk(a2, a3);
        cwb[rq][0] = cvtpk(b0, b1); cwb[rq][1] = cvtpk(b2, b3);
      }
      lsum += psum;
      // exchange: lane sends the word-pair its partner (l^32) needs
      unsigned ya0 = __shfl_xor(hh ? cwa[0][0] : cwa[1][0], 32);
      unsigned ya1 = __shfl_xor(hh ? cwa[0][1] : cwa[1][1], 32);
      unsigned ya2 = __shfl_xor(hh ? cwa[2][0] : cwa[3][0], 32);
      unsigned ya3 = __shfl_xor(hh ? cwa[2][1] : cwa[3][1], 32);
      unsigned yb0 = __shfl_xor(hh ? cwb[0][0] : cwb[1][0], 32);
      unsigned yb1 = __shfl_xor(hh ? cwb[0][1] : cwb[1][1], 32);
      unsigned yb2 = __shfl_xor(hh ? cwb[2][0] : cwb[3][0], 32);
      unsigned yb3 = __shfl_xor(hh ? cwb[2][1] : cwb[3][1], 32);
      short8 pa0 = hh ? mkfrag(ya0, ya1, cwa[1][0], cwa[1][1])
                      : mkfrag(cwa[0][0], cwa[0][1], ya0, ya1);
      short8 pa1 = hh ? mkfrag(ya2, ya3, cwa[3][0], cwa[3][1])
                      : mkfrag(cwa[2][0], cwa[2][1], ya2, ya3);
      short8 pb0 = hh ? mkfrag(yb0, yb1, cwb[1][0], cwb[1][1])
                      : mkfrag(cwb[0][0], cwb[0][1], yb0, yb1);
      short8 pb1 = hh ? mkfrag(yb2, yb3, cwb[3][0], cwb[3][1])
                      : mkfrag(cwb[2][0], cwb[2][1], yb2, yb3);

      // ---- PV: O^T[d][q] += mfma(V^T rows (k=t), P rows (k=t)) ----
      {
        short8 av;
        av = lds_rd(vbuf[cur], lq,      0  + hh*16); acc0 = mfma32(av, pa0, acc0);
        av = lds_rd(vbuf[cur], 32 + lq, 0  + hh*16); acc1 = mfma32(av, pa0, acc1);
        av = lds_rd(vbuf[cur], lq,      32 + hh*16); acc0 = mfma32(av, pa1, acc0);
        av = lds_rd(vbuf[cur], 32 + lq, 32 + hh*16); acc1 = mfma32(av, pa1, acc1);
        av = lds_rd(vbuf[cur], lq,      64 + hh*16); acc0 = mfma32(av, pb0, acc0);
        av = lds_rd(vbuf[cur], 32 + lq, 64 + hh*16); acc1 = mfma32(av, pb0, acc1);
        av = lds_rd(vbuf[cur], lq,      96 + hh*16); acc0 = mfma32(av, pb1, acc0);
        av = lds_rd(vbuf[cur], 32 + lq, 96 + hh*16); acc1 = mfma32(av, pb1, acc1);
      }
    }
    __syncthreads();
    cur ^= 1;
  }

  // ---- epilogue: normalize, transpose via per-wave swizzled scratch, store ----
  lsum += __shfl_xor(lsum, 32);
  const float inv = 1.f / lsum;
  u16* scr = ((u16*)kbuf) + w*2048;   // 4KB per wave ([32 q][64 d] bf16, swizzled)
#pragma unroll
  for (int dt = 0; dt < 2; ++dt)
#pragma unroll
    for (int rq = 0; rq < 4; ++rq) {
      float v0 = (dt ? acc1[4*rq+0] : acc0[4*rq+0]) * inv;
      float v1 = (dt ? acc1[4*rq+1] : acc0[4*rq+1]) * inv;
      float v2 = (dt ? acc1[4*rq+2] : acc0[4*rq+2]) * inv;
      float v3 = (dt ? acc1[4*rq+3] : acc0[4*rq+3]) * inv;
      const int dby = dt*64 + rq*16 + hh*8;       // byte offset of d in row
      const int by = lq*128 + ((dby) ^ ((lq & 7) << 4));
      *(unsigned*)((char*)scr + by)     = cvtpk(v0, v1);
      *(unsigned*)((char*)scr + by + 4) = cvtpk(v2, v3);
    }
#pragma unroll
  for (int qq = 0; qq < 4; ++qq) {
    const int qrow = qq*8 + (l >> 3);
    const int by = qrow*128 + (((l & 7) << 4) ^ ((qrow & 7) << 4));
    short8 v = *(const short8*)((const char*)scr + by);
    *(short8*)&O[(size_t)(q0 + qrow)*1024 + h*64 + (l & 7)*8] = v;
  }
}

// ---------- launch ----------
extern "C" void kernel_launch(void* const* d_in, const int* in_sizes, int n_in,
                              void* d_out, int out_size, void* d_ws, size_t ws_size,
                              hipStream_t stream) {
  const float* x    = (const float*)d_in[0];
  const float* freq = (const float*)d_in[1];
  const float* wq   = (const float*)d_in[2];
  const float* wqa  = (const float*)d_in[3];
  const float* wqb  = (const float*)d_in[4];
  const float* wk   = (const float*)d_in[5];
  const float* wka  = (const float*)d_in[6];
  const float* wkb  = (const float*)d_in[7];
  const float* wv   = (const float*)d_in[8];
  const float* wva  = (const float*)d_in[9];
  const float* wvb  = (const float*)d_in[10];
  const float* wo   = (const float*)d_in[11];
  const float* wos  = (const float*)d_in[12];
  float* out = (float*)d_out;

  char* ws = (char*)d_ws;
  u16*  x_bf = (u16*)ws;
  u16*  Qb   = (u16*)ws;                  // reuses x_bf region (stream-ordered)
  u16*  Kbuf = (u16*)(ws + (4u<<20));
  u16*  Vtb  = (u16*)(ws + (5u<<20));
  u16*  W1   = (u16*)(ws + (8u<<20));
  u16*  Weff = (u16*)(ws + (9u<<20));
  float* proj = (float*)(ws + (13u<<20));
  u16*  Obf  = (u16*)(ws + (13u<<20));    // reuses proj region

  k_prep    <<<3328, 256, 0, stream>>>(x, wq, wk, wv, wqa, wka, wva, wo, wos,
                                       x_bf, W1, Weff);
  k_gemm_bt<128,64><<<dim3(4,16,4), 256, 0, stream>>>(x_bf, W1, proj, 2048, 256, 2048, 512);
  k_expand  <<<dim3(2048,24), 64, 0, stream>>>(proj, wqb, wkb, wvb, freq, Qb, Kbuf, Vtb);
  k_attn    <<<dim3(16,16), 256, 0, stream>>>(Qb, Kbuf, Vtb, Obf);
  k_gemm_bt<128,128><<<dim3(16,16,1), 256, 0, stream>>>(Obf, Weff, out, 2048, 2048, 1024, 1024);
}

// Round 4
// 100.373 us; speedup vs baseline: 2.0880x; 1.3452x over previous
//
#include <hip/hip_runtime.h>
#include <hip/hip_bf16.h>

#define DEV __device__ __forceinline__

typedef unsigned short u16;
typedef __attribute__((ext_vector_type(8))) short short8;   // 8 bf16 (4 VGPRs)
typedef __attribute__((ext_vector_type(4))) float f32x4;    // 16x16 MFMA C/D
typedef __attribute__((ext_vector_type(16))) float f32x16;  // 32x32 MFMA C/D

// ---------- helpers ----------
DEV u16 f2bf(float f) {               // RNE float -> bf16 bits
  union { float f; unsigned u; } v; v.f = f;
  unsigned r = v.u + 0x7FFFu + ((v.u >> 16) & 1u);
  return (u16)(r >> 16);
}

DEV unsigned cvtpk(float lo, float hi) {  // packed bf16x2 (RNE)
  unsigned r;
  asm("v_cvt_pk_bf16_f32 %0, %1, %2" : "=v"(r) : "v"(lo), "v"(hi));
  return r;
}

DEV void async_ld16(const u16* g, u16* l) {
  __builtin_amdgcn_global_load_lds((__attribute__((address_space(1))) void*)g,
                                   (__attribute__((address_space(3))) void*)l,
                                   16, 0, 0);
}

DEV f32x4 mfma16(short8 a, short8 b, f32x4 c) {
  return __builtin_amdgcn_mfma_f32_16x16x32_bf16(a, b, c, 0, 0, 0);
}
DEV f32x16 mfma32(short8 a, short8 b, f32x16 c) {
  return __builtin_amdgcn_mfma_f32_32x32x16_bf16(a, b, c, 0, 0, 0);
}

DEV short8 mkfrag(unsigned w0, unsigned w1, unsigned w2, unsigned w3) {
  union { unsigned u[4]; short8 s; } u;
  u.u[0] = w0; u.u[1] = w1; u.u[2] = w2; u.u[3] = w3;
  return u.s;
}

// swizzled LDS b128 read from a [rows][64] bf16 tile (128B rows)
DEV short8 lds_rd(const u16* buf, int row, int colb) {
  return *(const short8*)((const char*)buf + row*128 + (colb ^ ((row & 7) << 4)));
}

#define QSCALE (0.125f * 1.4426950408889634f)

// ---------- kernel 1: fused prep (x->bf16 | W1 | Weff) ----------
__global__ __launch_bounds__(256) void k_prep(const float* __restrict__ x,
    const float* __restrict__ wq, const float* __restrict__ wk,
    const float* __restrict__ wv, const float* __restrict__ wqa,
    const float* __restrict__ wka, const float* __restrict__ wva,
    const float* __restrict__ wo, const float* __restrict__ wos,
    u16* __restrict__ xb, u16* __restrict__ W1, u16* __restrict__ Weff) {
  const int bid = blockIdx.x;
  if (bid < 1024) {                     // x fp32 -> bf16 (1048576 float4)
    int i = bid*256 + threadIdx.x;
    for (; i < 1048576; i += 1024*256) {
      float4 v = ((const float4*)x)[i];
      ushort4 o;
      o.x = f2bf(v.x); o.y = f2bf(v.y); o.z = f2bf(v.z); o.w = f2bf(v.w);
      ((ushort4*)xb)[i] = o;
    }
  } else if (bid < 1280) {              // W1 row
    const int row = bid - 1024;
    const float* src = nullptr; float sc = 1.f;
    if (row < 64)       { src = wq  + row*2048;       sc = QSCALE; }
    else if (row < 128) { src = wk  + (row-64)*2048;  }
    else if (row < 192) { src = wv  + (row-128)*2048; }
    else if (row < 200) { src = wqa + (row-192)*2048; sc = 2.f*QSCALE; }
    else if (row < 208) { src = wka + (row-200)*2048; sc = 2.f; }
    else if (row < 216) { src = wva + (row-208)*2048; sc = 2.f; }
    for (int c = threadIdx.x; c < 2048; c += 256)
      W1[row*2048 + c] = src ? f2bf(src[c]*sc) : (u16)0;
  } else {                              // Weff row
    const int e = bid - 1280;
    for (int f = threadIdx.x; f < 1024; f += 256)
      Weff[e*1024 + f] = f2bf(wos[e*1024 + f] + wo[e*64 + (f & 63)]);
  }
}

// ---------- GEMM: C[M][N] = A[M][K] * B[N][K]^T, bf16 in / fp32 out ----------
// 512 threads / 8 waves (2 waves/SIMD for latency hiding), 2-barrier K-loop.
template<int BM, int BN>
__global__ __launch_bounds__(512)
void k_gemm_bt(const u16* __restrict__ A, const u16* __restrict__ B,
               float* __restrict__ C, int M, int N, int K, int kslice) {
  constexpr int BK = 32;
  constexpr int NWC = (BN >= 128) ? 4 : 2;      // wave grid cols
  constexpr int NWR = 8 / NWC;                  // wave grid rows
  constexpr int WM = BM / NWR, WN = BN / NWC;
  constexpr int FM = WM/16, FN = WN/16;
  __shared__ u16 As[BM*BK];
  __shared__ u16 Bs[BN*BK];
  const int tid = threadIdx.x;
  const int w = tid >> 6, l = tid & 63;
  const int wm = (w / NWC)*WM, wn = (w % NWC)*WN;
  const int tm = blockIdx.y*BM, tn = blockIdx.x*BN;
  const int k0 = blockIdx.z * kslice;
  C += (size_t)blockIdx.z * M * N;
  const int lr = l >> 2;
  const int lk = (l & 3)*8;
  const int la = l & 15, lko = (l >> 4)*8;

  f32x4 acc[FM][FN];
#pragma unroll
  for (int i = 0; i < FM; ++i)
#pragma unroll
    for (int j = 0; j < FN; ++j) acc[i][j] = (f32x4){0.f,0.f,0.f,0.f};

  const int nk = kslice / BK;
  for (int kt = 0; kt < nk; ++kt) {
    const int kk = k0 + kt*BK + lk;
    async_ld16(A + (size_t)(tm + w*16 + lr)*K + kk, &As[w*512]);
    if (w < BN/16)
      async_ld16(B + (size_t)(tn + w*16 + lr)*K + kk, &Bs[w*512]);
    __syncthreads();
    short8 af[FM], bfr[FN];
#pragma unroll
    for (int mi = 0; mi < FM; ++mi)
      af[mi] = *(const short8*)&As[(wm + mi*16 + la)*BK + lko];
#pragma unroll
    for (int ni = 0; ni < FN; ++ni)
      bfr[ni] = *(const short8*)&Bs[(wn + ni*16 + la)*BK + lko];
#pragma unroll
    for (int mi = 0; mi < FM; ++mi)
#pragma unroll
      for (int ni = 0; ni < FN; ++ni)
        acc[mi][ni] = mfma16(af[mi], bfr[ni], acc[mi][ni]);
    __syncthreads();
  }
#pragma unroll
  for (int mi = 0; mi < FM; ++mi)
#pragma unroll
    for (int ni = 0; ni < FN; ++ni) {
      const int r0 = tm + wm + mi*16 + (l >> 4)*4;
      const int cc = tn + wn + ni*16 + la;
#pragma unroll
      for (int r = 0; r < 4; ++r)
        C[(size_t)(r0 + r)*N + cc] = acc[mi][ni][r];
    }
}

// ---------- kernel: expand base+LoRA, RoPE, write Q/K/V (bf16) ----------
__global__ __launch_bounds__(64)
void k_expand(const float* __restrict__ proj, const float* __restrict__ wqb,
              const float* __restrict__ wkb, const float* __restrict__ wvb,
              const float* __restrict__ freq, u16* __restrict__ Q,
              u16* __restrict__ Kb, u16* __restrict__ Vt) {
  const int s = blockIdx.x;
  const int slot = blockIdx.y;
  const int d = threadIdx.x;
  const float* pr = proj + s*256;
  int bcol, tb; const float* wb;
  if (slot < 16)      { bcol = 0;   tb = 192; wb = wqb + (slot*64 + d)*8; }
  else if (slot < 20) { bcol = 64;  tb = 200; wb = wkb + ((slot-16)*64 + d)*8; }
  else                { bcol = 128; tb = 208; wb = wvb + ((slot-20)*64 + d)*8; }
  float base = 0.f, t[8];
#pragma unroll
  for (int r = 0; r < 8; ++r) t[r] = 0.f;
#pragma unroll
  for (int p = 0; p < 4; ++p) {
    const float* pp = pr + p*524288;
    base += pp[bcol + d];
#pragma unroll
    for (int r = 0; r < 8; ++r) t[r] += pp[tb + r];
  }
  float val = base;
#pragma unroll
  for (int r = 0; r < 8; ++r) val += t[r]*wb[r];
  if (slot < 20) {  // RoPE (Q and K)
    float partner = __shfl_xor(val, 1);
    float c  = freq[s*64 + (d >> 1)*2];
    float sn = freq[s*64 + (d >> 1)*2 + 1];
    val = (d & 1) ? (partner*sn + val*c) : (val*c - partner*sn);
  }
  u16 o = f2bf(val);
  if (slot < 16)      Q [((size_t)slot*2048 + s)*64 + d] = o;
  else if (slot < 20) Kb[((size_t)(slot-16)*2048 + s)*64 + d] = o;
  else                Vt[(size_t)(slot-20)*131072 + d*2048 + s] = o;
}

// ---------- kernel: causal flash attention (v4) ----------
// QBLK=64, grid 32qt x 16h = 512 blocks; 4 waves = 2 q-halves x 2 t-parity
// groups; per-parity double-buffered K/V LDS; in-block flash combine.
__global__ __launch_bounds__(256)
void k_attn(const u16* __restrict__ Q, const u16* __restrict__ Kb,
            const u16* __restrict__ Vt, u16* __restrict__ O) {
  __shared__ u16 smem[4][2][4096];   // [par*2+kv][dbuf][8KB tile]  = 64KB
  const int tid = threadIdx.x;
  const int w = tid >> 6, l = tid & 63;
  const int qhalf = w & 1, par = w >> 1;
  const int bid = blockIdx.x;
  const int h = bid & 15, kh = h >> 2;
  const int z = bid >> 4;
  const int qt = (z < 16) ? (31 - z) : (z - 16);   // per-CU work pairing
  const int q0w = qt*64 + qhalf*32;
  const int lq = l & 31, hh = l >> 5;
  const int qg = q0w + lq;

  u16* kb0 = smem[par*2][0];   u16* kb1 = smem[par*2][1];
  u16* vb0 = smem[par*2+1][0]; u16* vb1 = smem[par*2+1][1];

  const u16* Qh = Q  + (size_t)h *131072;
  const u16* Kh = Kb + (size_t)kh*131072;
  const u16* Vh = Vt + (size_t)kh*131072;

  // Q as B-fragments: lane holds row q=qg, k-slot hh*8, 4 k-steps of 16
  short8 bq[4];
#pragma unroll
  for (int ks = 0; ks < 4; ++ks)
    bq[ks] = *(const short8*)&Qh[qg*64 + ks*16 + hh*8];

  f32x16 acc0, acc1;                // O^T [d][q]
#pragma unroll
  for (int r = 0; r < 16; ++r) { acc0[r] = 0.f; acc1[r] = 0.f; }
  float m = -1e30f, lsum = 0.f;

  // staging: wave covers rows qhalf*32..+31 of each 64-row tile, 4 calls
  const int srow = qhalf*32 + (l >> 3);
  const int scol = ((l & 7) ^ (l >> 3)) * 8;       // inverse-swizzled src col
  const int sbase = qhalf*2048;                    // u16 offset in tile

  const int nt = qt + 1;
  const int ITER = (nt + 1) >> 1;

  // prologue: stage tile tt=par into buf0 (addresses always in-bounds)
  {
    const int t0p = par*64;
#pragma unroll
    for (int j = 0; j < 4; ++j) {
      async_ld16(Kh + (size_t)(t0p + srow + j*8)*64 + scol, &kb0[sbase + j*512]);
      async_ld16(Vh + (size_t)(srow + j*8)*2048 + t0p + scol, &vb0[sbase + j*512]);
    }
  }
  __syncthreads();

  int cur = 0;
  for (int it = 0; it < ITER; ++it) {
    const int tt = 2*it + par;
    const int t0 = tt*64;
    if (tt + 2 < nt) {                     // prefetch this parity's next tile
      const int tn0 = t0 + 128;
      u16* kn = cur ? kb0 : kb1;
      u16* vn = cur ? vb0 : vb1;
#pragma unroll
      for (int j = 0; j < 4; ++j) {
        async_ld16(Kh + (size_t)(tn0 + srow + j*8)*64 + scol, &kn[sbase + j*512]);
        async_ld16(Vh + (size_t)(srow + j*8)*2048 + tn0 + scol, &vn[sbase + j*512]);
      }
    }

    if (tt < nt) {                         // parity-1 guard on final odd iter
      const u16* kc = cur ? kb1 : kb0;
      const u16* vc = cur ? vb1 : vb0;
      // ---- QK^T swapped: S^T[t][q] = mfma(K rows, Q rows) ----
      f32x16 s0, s1;
#pragma unroll
      for (int r = 0; r < 16; ++r) { s0[r] = 0.f; s1[r] = 0.f; }
#pragma unroll
      for (int ks = 0; ks < 4; ++ks) {
        short8 ak0 = lds_rd(kc, lq,      ks*32 + hh*16);
        short8 ak1 = lds_rd(kc, 32 + lq, ks*32 + hh*16);
        s0 = mfma32(ak0, bq[ks], s0);
        s1 = mfma32(ak1, bq[ks], s1);
      }
      // ---- causal mask ----
      if (t0 + 63 > q0w) {
#pragma unroll
        for (int r = 0; r < 16; ++r) {
          const int tl = (r & 3) + ((r >> 2) << 3) + (hh << 2);
          if (t0 + tl > qg)      s0[r] = -1e30f;
          if (t0 + 32 + tl > qg) s1[r] = -1e30f;
        }
      }
      // ---- in-register max + one cross-half exchange ----
      float mx8[8];
#pragma unroll
      for (int r = 0; r < 8; ++r)
        mx8[r] = fmaxf(fmaxf(s0[r], s0[r+8]), fmaxf(s1[r], s1[r+8]));
      float mx = fmaxf(fmaxf(fmaxf(mx8[0], mx8[1]), fmaxf(mx8[2], mx8[3])),
                       fmaxf(fmaxf(mx8[4], mx8[5]), fmaxf(mx8[6], mx8[7])));
      mx = fmaxf(mx, __shfl_xor(mx, 32));
      const float mnew = fmaxf(m, mx);
      const float al = exp2f(m - mnew);
      m = mnew;
#pragma unroll
      for (int r = 0; r < 16; ++r) { acc0[r] *= al; acc1[r] *= al; }
      lsum *= al;

      // ---- P = exp2(S - m), packed bf16x2, in-register redistribution ----
      unsigned cwa[4][2], cwb[4][2];
      float psum = 0.f;
#pragma unroll
      for (int rq = 0; rq < 4; ++rq) {
        float a0 = exp2f(s0[4*rq+0] - mnew), a1 = exp2f(s0[4*rq+1] - mnew);
        float a2 = exp2f(s0[4*rq+2] - mnew), a3 = exp2f(s0[4*rq+3] - mnew);
        float b0 = exp2f(s1[4*rq+0] - mnew), b1 = exp2f(s1[4*rq+1] - mnew);
        float b2 = exp2f(s1[4*rq+2] - mnew), b3 = exp2f(s1[4*rq+3] - mnew);
        psum += (a0+a1) + (a2+a3) + (b0+b1) + (b2+b3);
        cwa[rq][0] = cvtpk(a0, a1); cwa[rq][1] = cvtpk(a2, a3);
        cwb[rq][0] = cvtpk(b0, b1); cwb[rq][1] = cvtpk(b2, b3);
      }
      lsum += psum;
      unsigned ya0 = __shfl_xor(hh ? cwa[0][0] : cwa[1][0], 32);
      unsigned ya1 = __shfl_xor(hh ? cwa[0][1] : cwa[1][1], 32);
      unsigned ya2 = __shfl_xor(hh ? cwa[2][0] : cwa[3][0], 32);
      unsigned ya3 = __shfl_xor(hh ? cwa[2][1] : cwa[3][1], 32);
      unsigned yb0 = __shfl_xor(hh ? cwb[0][0] : cwb[1][0], 32);
      unsigned yb1 = __shfl_xor(hh ? cwb[0][1] : cwb[1][1], 32);
      unsigned yb2 = __shfl_xor(hh ? cwb[2][0] : cwb[3][0], 32);
      unsigned yb3 = __shfl_xor(hh ? cwb[2][1] : cwb[3][1], 32);
      short8 pa0 = hh ? mkfrag(ya0, ya1, cwa[1][0], cwa[1][1])
                      : mkfrag(cwa[0][0], cwa[0][1], ya0, ya1);
      short8 pa1 = hh ? mkfrag(ya2, ya3, cwa[3][0], cwa[3][1])
                      : mkfrag(cwa[2][0], cwa[2][1], ya2, ya3);
      short8 pb0 = hh ? mkfrag(yb0, yb1, cwb[1][0], cwb[1][1])
                      : mkfrag(cwb[0][0], cwb[0][1], yb0, yb1);
      short8 pb1 = hh ? mkfrag(yb2, yb3, cwb[3][0], cwb[3][1])
                      : mkfrag(cwb[2][0], cwb[2][1], yb2, yb3);

      // ---- PV: O^T[d][q] += mfma(V^T rows (k=t), P rows (k=t)) ----
      {
        short8 av;
        av = lds_rd(vc, lq,      0  + hh*16); acc0 = mfma32(av, pa0, acc0);
        av = lds_rd(vc, 32 + lq, 0  + hh*16); acc1 = mfma32(av, pa0, acc1);
        av = lds_rd(vc, lq,      32 + hh*16); acc0 = mfma32(av, pa1, acc0);
        av = lds_rd(vc, 32 + lq, 32 + hh*16); acc1 = mfma32(av, pa1, acc1);
        av = lds_rd(vc, lq,      64 + hh*16); acc0 = mfma32(av, pb0, acc0);
        av = lds_rd(vc, 32 + lq, 64 + hh*16); acc1 = mfma32(av, pb0, acc1);
        av = lds_rd(vc, lq,      96 + hh*16); acc0 = mfma32(av, pb1, acc0);
        av = lds_rd(vc, 32 + lq, 96 + hh*16); acc1 = mfma32(av, pb1, acc1);
      }
    }
    __syncthreads();
    cur ^= 1;
  }

  // ---- in-block flash combine: parity1 -> parity0 via LDS ----
  float* combuf = (float*)smem;                 // 2 pairs x 34 x 64 f32
  float* cb = combuf + qhalf*34*64;
  if (par == 1) {
    cb[l] = m; cb[64 + l] = lsum;
#pragma unroll
    for (int r = 0; r < 16; ++r) {
      cb[(2+r)*64 + l]  = acc0[r];
      cb[(18+r)*64 + l] = acc1[r];
    }
  }
  __syncthreads();
  if (par == 0) {
    const float m1 = cb[l], ls1 = cb[64 + l];
    const float mm = fmaxf(m, m1);
    const float a0 = exp2f(m - mm), a1 = exp2f(m1 - mm);
    lsum = lsum*a0 + ls1*a1;
#pragma unroll
    for (int r = 0; r < 16; ++r) {
      acc0[r] = acc0[r]*a0 + cb[(2+r)*64 + l]*a1;
      acc1[r] = acc1[r]*a0 + cb[(18+r)*64 + l]*a1;
    }
    lsum += __shfl_xor(lsum, 32);
    const float inv = 1.f / lsum;

    // epilogue: transpose O^T -> O via per-wave swizzled scratch (parity1 K region)
    u16* scr = &smem[2][0][0] + qhalf*2048;     // 4KB per parity0 wave
#pragma unroll
    for (int dt = 0; dt < 2; ++dt)
#pragma unroll
      for (int rq = 0; rq < 4; ++rq) {
        float v0 = (dt ? acc1[4*rq+0] : acc0[4*rq+0]) * inv;
        float v1 = (dt ? acc1[4*rq+1] : acc0[4*rq+1]) * inv;
        float v2 = (dt ? acc1[4*rq+2] : acc0[4*rq+2]) * inv;
        float v3 = (dt ? acc1[4*rq+3] : acc0[4*rq+3]) * inv;
        const int dby = dt*64 + rq*16 + hh*8;
        const int by = lq*128 + (dby ^ ((lq & 7) << 4));
        *(unsigned*)((char*)scr + by)     = cvtpk(v0, v1);
        *(unsigned*)((char*)scr + by + 4) = cvtpk(v2, v3);
      }
#pragma unroll
    for (int qq = 0; qq < 4; ++qq) {
      const int qrow = qq*8 + (l >> 3);
      const int by = qrow*128 + (((l & 7) << 4) ^ ((qrow & 7) << 4));
      short8 v = *(const short8*)((const char*)scr + by);
      *(short8*)&O[(size_t)(q0w + qrow)*1024 + h*64 + (l & 7)*8] = v;
    }
  }
}

// ---------- launch ----------
extern "C" void kernel_launch(void* const* d_in, const int* in_sizes, int n_in,
                              void* d_out, int out_size, void* d_ws, size_t ws_size,
                              hipStream_t stream) {
  const float* x    = (const float*)d_in[0];
  const float* freq = (const float*)d_in[1];
  const float* wq   = (const float*)d_in[2];
  const float* wqa  = (const float*)d_in[3];
  const float* wqb  = (const float*)d_in[4];
  const float* wk   = (const float*)d_in[5];
  const float* wka  = (const float*)d_in[6];
  const float* wkb  = (const float*)d_in[7];
  const float* wv   = (const float*)d_in[8];
  const float* wva  = (const float*)d_in[9];
  const float* wvb  = (const float*)d_in[10];
  const float* wo   = (const float*)d_in[11];
  const float* wos  = (const float*)d_in[12];
  float* out = (float*)d_out;

  char* ws = (char*)d_ws;
  u16*  x_bf = (u16*)ws;
  u16*  Qb   = (u16*)ws;                  // reuses x_bf region (stream-ordered)
  u16*  Kbuf = (u16*)(ws + (4u<<20));
  u16*  Vtb  = (u16*)(ws + (5u<<20));
  u16*  W1   = (u16*)(ws + (8u<<20));
  u16*  Weff = (u16*)(ws + (9u<<20));
  float* proj = (float*)(ws + (13u<<20));
  u16*  Obf  = (u16*)(ws + (13u<<20));    // reuses proj region

  k_prep    <<<3328, 256, 0, stream>>>(x, wq, wk, wv, wqa, wka, wva, wo, wos,
                                       x_bf, W1, Weff);
  k_gemm_bt<128,64><<<dim3(4,16,4), 512, 0, stream>>>(x_bf, W1, proj, 2048, 256, 2048, 512);
  k_expand  <<<dim3(2048,24), 64, 0, stream>>>(proj, wqb, wkb, wvb, freq, Qb, Kbuf, Vtb);
  k_attn    <<<dim3(512), 256, 0, stream>>>(Qb, Kbuf, Vtb, Obf);
  k_gemm_bt<128,128><<<dim3(16,16,1), 512, 0, stream>>>(Obf, Weff, out, 2048, 2048, 1024, 1024);
}

// Round 5
// 89.397 us; speedup vs baseline: 2.3444x; 1.1228x over previous
//
#include <hip/hip_runtime.h>
#include <hip/hip_bf16.h>

#define DEV __device__ __forceinline__

typedef unsigned short u16;
typedef __attribute__((ext_vector_type(8))) short short8;   // 8 bf16 (4 VGPRs)
typedef __attribute__((ext_vector_type(4))) float f32x4;    // 16x16 MFMA C/D
typedef __attribute__((ext_vector_type(16))) float f32x16;  // 32x32 MFMA C/D

// ---------- helpers ----------
DEV u16 f2bf(float f) {               // RNE float -> bf16 bits
  union { float f; unsigned u; } v; v.f = f;
  unsigned r = v.u + 0x7FFFu + ((v.u >> 16) & 1u);
  return (u16)(r >> 16);
}

DEV unsigned cvtpk(float lo, float hi) {  // packed bf16x2 (RNE)
  unsigned r;
  asm("v_cvt_pk_bf16_f32 %0, %1, %2" : "=v"(r) : "v"(lo), "v"(hi));
  return r;
}

DEV void async_ld16(const u16* g, u16* l) {
  __builtin_amdgcn_global_load_lds((__attribute__((address_space(1))) void*)g,
                                   (__attribute__((address_space(3))) void*)l,
                                   16, 0, 0);
}

DEV f32x4 mfma16(short8 a, short8 b, f32x4 c) {
  return __builtin_amdgcn_mfma_f32_16x16x32_bf16(a, b, c, 0, 0, 0);
}
DEV f32x16 mfma32(short8 a, short8 b, f32x16 c) {
  return __builtin_amdgcn_mfma_f32_32x32x16_bf16(a, b, c, 0, 0, 0);
}

DEV short8 mkfrag(unsigned w0, unsigned w1, unsigned w2, unsigned w3) {
  union { unsigned u[4]; short8 s; } u;
  u.u[0] = w0; u.u[1] = w1; u.u[2] = w2; u.u[3] = w3;
  return u.s;
}

// swizzled LDS b128 read from a [rows][64] bf16 tile (128B rows, st-style XOR)
DEV short8 lds_rd(const u16* buf, int row, int colb) {
  return *(const short8*)((const char*)buf + row*128 + (colb ^ ((row & 7) << 4)));
}

#define QSCALE (0.125f * 1.4426950408889634f)

// ---------- kernel 1: fused prep (x->bf16 | W1 | Weff) ----------
__global__ __launch_bounds__(256) void k_prep(const float* __restrict__ x,
    const float* __restrict__ wq, const float* __restrict__ wk,
    const float* __restrict__ wv, const float* __restrict__ wqa,
    const float* __restrict__ wka, const float* __restrict__ wva,
    const float* __restrict__ wo, const float* __restrict__ wos,
    u16* __restrict__ xb, u16* __restrict__ W1, u16* __restrict__ Weff) {
  const int bid = blockIdx.x;
  if (bid < 1024) {                     // x fp32 -> bf16 (1048576 float4)
    int i = bid*256 + threadIdx.x;
    for (; i < 1048576; i += 1024*256) {
      float4 v = ((const float4*)x)[i];
      ushort4 o;
      o.x = f2bf(v.x); o.y = f2bf(v.y); o.z = f2bf(v.z); o.w = f2bf(v.w);
      ((ushort4*)xb)[i] = o;
    }
  } else if (bid < 1280) {              // W1 row
    const int row = bid - 1024;
    const float* src = nullptr; float sc = 1.f;
    if (row < 64)       { src = wq  + row*2048;       sc = QSCALE; }
    else if (row < 128) { src = wk  + (row-64)*2048;  }
    else if (row < 192) { src = wv  + (row-128)*2048; }
    else if (row < 200) { src = wqa + (row-192)*2048; sc = 2.f*QSCALE; }
    else if (row < 208) { src = wka + (row-200)*2048; sc = 2.f; }
    else if (row < 216) { src = wva + (row-208)*2048; sc = 2.f; }
    for (int c = threadIdx.x; c < 2048; c += 256)
      W1[row*2048 + c] = src ? f2bf(src[c]*sc) : (u16)0;
  } else {                              // Weff row
    const int e = bid - 1280;
    for (int f = threadIdx.x; f < 1024; f += 256)
      Weff[e*1024 + f] = f2bf(wos[e*1024 + f] + wo[e*64 + (f & 63)]);
  }
}

// ---------- GEMM v2: C[M][N] = A[M][K]*B[N][K]^T, BK=64, swizzled LDS ----------
// 512 threads / 8 waves; T2 XOR-swizzle (conflict-free frag reads); 2-barrier loop.
template<int BM, int BN>
__global__ __launch_bounds__(512)
void k_gemm_bt(const u16* __restrict__ A, const u16* __restrict__ B,
               float* __restrict__ C, int M, int N, int K, int kslice) {
  constexpr int NWC = (BN >= 128) ? 4 : 2;      // wave grid cols
  constexpr int NWR = 8 / NWC;                  // wave grid rows
  constexpr int WM = BM / NWR, WN = BN / NWC;
  constexpr int FM = WM/16, FN = WN/16;
  __shared__ u16 As[BM*64];                     // [row][64], 128B rows, swizzled
  __shared__ u16 Bs[BN*64];
  const int tid = threadIdx.x;
  const int w = tid >> 6, l = tid & 63;
  const int wm = (w / NWC)*WM, wn = (w % NWC)*WN;
  const int tm = blockIdx.y*BM, tn = blockIdx.x*BN;
  const int k0 = blockIdx.z * kslice;
  C += (size_t)blockIdx.z * M * N;
  const int sr = (w << 3) + (l >> 3);           // staging row (per 64-row call)
  const int sc = (((l & 7) ^ (l >> 3)) << 3);   // inverse-swizzled src col (u16)
  const int la = l & 15, lg = l >> 4;

  f32x4 acc[FM][FN];
#pragma unroll
  for (int i = 0; i < FM; ++i)
#pragma unroll
    for (int j = 0; j < FN; ++j) acc[i][j] = (f32x4){0.f,0.f,0.f,0.f};

  const int nk = kslice >> 6;
  for (int kt = 0; kt < nk; ++kt) {
    const int kk = k0 + (kt << 6);
#pragma unroll
    for (int j = 0; j < BM/64; ++j)
      async_ld16(A + (size_t)(tm + j*64 + sr)*K + kk + sc, &As[(j*64 + w*8)*64]);
#pragma unroll
    for (int j = 0; j < BN/64; ++j)
      async_ld16(B + (size_t)(tn + j*64 + sr)*K + kk + sc, &Bs[(j*64 + w*8)*64]);
    __syncthreads();
    short8 af[FM][2], bfr[FN][2];
#pragma unroll
    for (int mi = 0; mi < FM; ++mi)
#pragma unroll
      for (int ks = 0; ks < 2; ++ks)
        af[mi][ks] = lds_rd(As, wm + mi*16 + la, ks*64 + lg*16);
#pragma unroll
    for (int ni = 0; ni < FN; ++ni)
#pragma unroll
      for (int ks = 0; ks < 2; ++ks)
        bfr[ni][ks] = lds_rd(Bs, wn + ni*16 + la, ks*64 + lg*16);
#pragma unroll
    for (int ks = 0; ks < 2; ++ks)
#pragma unroll
      for (int mi = 0; mi < FM; ++mi)
#pragma unroll
        for (int ni = 0; ni < FN; ++ni)
          acc[mi][ni] = mfma16(af[mi][ks], bfr[ni][ks], acc[mi][ni]);
    __syncthreads();
  }
#pragma unroll
  for (int mi = 0; mi < FM; ++mi)
#pragma unroll
    for (int ni = 0; ni < FN; ++ni) {
      const int r0 = tm + wm + mi*16 + lg*4;
      const int cc = tn + wn + ni*16 + la;
#pragma unroll
      for (int r = 0; r < 4; ++r)
        C[(size_t)(r0 + r)*N + cc] = acc[mi][ni][r];
    }
}

// ---------- kernel: expand base+LoRA, RoPE, write Q/K/V (v2: 256-thr blocks) ----------
__global__ __launch_bounds__(256)
void k_expand(const float* __restrict__ proj, const float* __restrict__ wqb,
              const float* __restrict__ wkb, const float* __restrict__ wvb,
              const float* __restrict__ freq, u16* __restrict__ Q,
              u16* __restrict__ Kb, u16* __restrict__ Vt) {
  __shared__ float prs[256];
  const int s = blockIdx.x;
  {
    const int c = threadIdx.x;
    const float* p0 = proj + s*256;
    prs[c] = (p0[c] + p0[c + 524288]) + (p0[c + 1048576] + p0[c + 1572864]);
  }
  __syncthreads();
  const int d = threadIdx.x & 63;
  const int w = threadIdx.x >> 6;
  const float cs = freq[s*64 + (d & 62)];
  const float sn = freq[s*64 + (d & 62) + 1];
#pragma unroll
  for (int pass = 0; pass < 6; ++pass) {
    const int slot = pass*4 + w;
    int bcol, tb; const float* wb;
    if (slot < 16)      { bcol = 0;   tb = 192; wb = wqb + (slot*64 + d)*8; }
    else if (slot < 20) { bcol = 64;  tb = 200; wb = wkb + ((slot-16)*64 + d)*8; }
    else                { bcol = 128; tb = 208; wb = wvb + ((slot-20)*64 + d)*8; }
    float val = prs[bcol + d];
#pragma unroll
    for (int r = 0; r < 8; ++r) val += prs[tb + r] * wb[r];
    if (slot < 20) {  // RoPE
      float partner = __shfl_xor(val, 1);
      val = (d & 1) ? (partner*sn + val*cs) : (val*cs - partner*sn);
    }
    u16 o = f2bf(val);
    if (slot < 16)      Q [((size_t)slot*2048 + s)*64 + d] = o;
    else if (slot < 20) Kb[((size_t)(slot-16)*2048 + s)*64 + d] = o;
    else                Vt[(size_t)(slot-20)*131072 + (size_t)d*2048 + s] = o;
  }
}

// ---------- kernel: causal flash attention (v5: +defer-max, +setprio) ----------
__global__ __launch_bounds__(256)
void k_attn(const u16* __restrict__ Q, const u16* __restrict__ Kb,
            const u16* __restrict__ Vt, u16* __restrict__ O) {
  __shared__ u16 smem[4][2][4096];   // [par*2+kv][dbuf][8KB tile]  = 64KB
  const int tid = threadIdx.x;
  const int w = tid >> 6, l = tid & 63;
  const int qhalf = w & 1, par = w >> 1;
  const int bid = blockIdx.x;
  const int h = bid & 15, kh = h >> 2;
  const int z = bid >> 4;
  const int qt = (z < 16) ? (31 - z) : (z - 16);   // per-CU work pairing
  const int q0w = qt*64 + qhalf*32;
  const int lq = l & 31, hh = l >> 5;
  const int qg = q0w + lq;

  u16* kb0 = smem[par*2][0];   u16* kb1 = smem[par*2][1];
  u16* vb0 = smem[par*2+1][0]; u16* vb1 = smem[par*2+1][1];

  const u16* Qh = Q  + (size_t)h *131072;
  const u16* Kh = Kb + (size_t)kh*131072;
  const u16* Vh = Vt + (size_t)kh*131072;

  short8 bq[4];
#pragma unroll
  for (int ks = 0; ks < 4; ++ks)
    bq[ks] = *(const short8*)&Qh[qg*64 + ks*16 + hh*8];

  f32x16 acc0, acc1;                // O^T [d][q]
#pragma unroll
  for (int r = 0; r < 16; ++r) { acc0[r] = 0.f; acc1[r] = 0.f; }
  float m = -1e30f, lsum = 0.f;

  const int srow = qhalf*32 + (l >> 3);
  const int scol = ((l & 7) ^ (l >> 3)) * 8;       // inverse-swizzled src col
  const int sbase = qhalf*2048;

  const int nt = qt + 1;
  const int ITER = (nt + 1) >> 1;

  {
    const int t0p = par*64;
#pragma unroll
    for (int j = 0; j < 4; ++j) {
      async_ld16(Kh + (size_t)(t0p + srow + j*8)*64 + scol, &kb0[sbase + j*512]);
      async_ld16(Vh + (size_t)(srow + j*8)*2048 + t0p + scol, &vb0[sbase + j*512]);
    }
  }
  __syncthreads();

  int cur = 0;
  for (int it = 0; it < ITER; ++it) {
    const int tt = 2*it + par;
    const int t0 = tt*64;
    if (tt + 2 < nt) {                     // prefetch this parity's next tile
      const int tn0 = t0 + 128;
      u16* kn = cur ? kb0 : kb1;
      u16* vn = cur ? vb0 : vb1;
#pragma unroll
      for (int j = 0; j < 4; ++j) {
        async_ld16(Kh + (size_t)(tn0 + srow + j*8)*64 + scol, &kn[sbase + j*512]);
        async_ld16(Vh + (size_t)(srow + j*8)*2048 + tn0 + scol, &vn[sbase + j*512]);
      }
    }

    if (tt < nt) {
      const u16* kc = cur ? kb1 : kb0;
      const u16* vc = cur ? vb1 : vb0;
      // ---- QK^T swapped: S^T[t][q] = mfma(K rows, Q rows) ----
      f32x16 s0, s1;
#pragma unroll
      for (int r = 0; r < 16; ++r) { s0[r] = 0.f; s1[r] = 0.f; }
      __builtin_amdgcn_s_setprio(1);
#pragma unroll
      for (int ks = 0; ks < 4; ++ks) {
        short8 ak0 = lds_rd(kc, lq,      ks*32 + hh*16);
        short8 ak1 = lds_rd(kc, 32 + lq, ks*32 + hh*16);
        s0 = mfma32(ak0, bq[ks], s0);
        s1 = mfma32(ak1, bq[ks], s1);
      }
      __builtin_amdgcn_s_setprio(0);
      // ---- causal mask ----
      if (t0 + 63 > q0w) {
#pragma unroll
        for (int r = 0; r < 16; ++r) {
          const int tl = (r & 3) + ((r >> 2) << 3) + (hh << 2);
          if (t0 + tl > qg)      s0[r] = -1e30f;
          if (t0 + 32 + tl > qg) s1[r] = -1e30f;
        }
      }
      // ---- in-register max + one cross-half exchange ----
      float mx8[8];
#pragma unroll
      for (int r = 0; r < 8; ++r)
        mx8[r] = fmaxf(fmaxf(s0[r], s0[r+8]), fmaxf(s1[r], s1[r+8]));
      float mx = fmaxf(fmaxf(fmaxf(mx8[0], mx8[1]), fmaxf(mx8[2], mx8[3])),
                       fmaxf(fmaxf(mx8[4], mx8[5]), fmaxf(mx8[6], mx8[7])));
      mx = fmaxf(mx, __shfl_xor(mx, 32));
      // ---- defer-max (T13): skip rescale when growth <= 8 (log2 domain) ----
      if (!__all(mx <= m + 8.f)) {
        const float mnew = fmaxf(m, mx);
        const float al = exp2f(m - mnew);
        m = mnew;
#pragma unroll
        for (int r = 0; r < 16; ++r) { acc0[r] *= al; acc1[r] *= al; }
        lsum *= al;
      }

      // ---- P = exp2(S - m), packed bf16x2, in-register redistribution ----
      unsigned cwa[4][2], cwb[4][2];
      float psum = 0.f;
#pragma unroll
      for (int rq = 0; rq < 4; ++rq) {
        float a0 = exp2f(s0[4*rq+0] - m), a1 = exp2f(s0[4*rq+1] - m);
        float a2 = exp2f(s0[4*rq+2] - m), a3 = exp2f(s0[4*rq+3] - m);
        float b0 = exp2f(s1[4*rq+0] - m), b1 = exp2f(s1[4*rq+1] - m);
        float b2 = exp2f(s1[4*rq+2] - m), b3 = exp2f(s1[4*rq+3] - m);
        psum += (a0+a1) + (a2+a3) + (b0+b1) + (b2+b3);
        cwa[rq][0] = cvtpk(a0, a1); cwa[rq][1] = cvtpk(a2, a3);
        cwb[rq][0] = cvtpk(b0, b1); cwb[rq][1] = cvtpk(b2, b3);
      }
      lsum += psum;
      unsigned ya0 = __shfl_xor(hh ? cwa[0][0] : cwa[1][0], 32);
      unsigned ya1 = __shfl_xor(hh ? cwa[0][1] : cwa[1][1], 32);
      unsigned ya2 = __shfl_xor(hh ? cwa[2][0] : cwa[3][0], 32);
      unsigned ya3 = __shfl_xor(hh ? cwa[2][1] : cwa[3][1], 32);
      unsigned yb0 = __shfl_xor(hh ? cwb[0][0] : cwb[1][0], 32);
      unsigned yb1 = __shfl_xor(hh ? cwb[0][1] : cwb[1][1], 32);
      unsigned yb2 = __shfl_xor(hh ? cwb[2][0] : cwb[3][0], 32);
      unsigned yb3 = __shfl_xor(hh ? cwb[2][1] : cwb[3][1], 32);
      short8 pa0 = hh ? mkfrag(ya0, ya1, cwa[1][0], cwa[1][1])
                      : mkfrag(cwa[0][0], cwa[0][1], ya0, ya1);
      short8 pa1 = hh ? mkfrag(ya2, ya3, cwa[3][0], cwa[3][1])
                      : mkfrag(cwa[2][0], cwa[2][1], ya2, ya3);
      short8 pb0 = hh ? mkfrag(yb0, yb1, cwb[1][0], cwb[1][1])
                      : mkfrag(cwb[0][0], cwb[0][1], yb0, yb1);
      short8 pb1 = hh ? mkfrag(yb2, yb3, cwb[3][0], cwb[3][1])
                      : mkfrag(cwb[2][0], cwb[2][1], yb2, yb3);

      // ---- PV: O^T[d][q] += mfma(V^T rows (k=t), P rows (k=t)) ----
      {
        short8 av;
        __builtin_amdgcn_s_setprio(1);
        av = lds_rd(vc, lq,      0  + hh*16); acc0 = mfma32(av, pa0, acc0);
        av = lds_rd(vc, 32 + lq, 0  + hh*16); acc1 = mfma32(av, pa0, acc1);
        av = lds_rd(vc, lq,      32 + hh*16); acc0 = mfma32(av, pa1, acc0);
        av = lds_rd(vc, 32 + lq, 32 + hh*16); acc1 = mfma32(av, pa1, acc1);
        av = lds_rd(vc, lq,      64 + hh*16); acc0 = mfma32(av, pb0, acc0);
        av = lds_rd(vc, 32 + lq, 64 + hh*16); acc1 = mfma32(av, pb0, acc1);
        av = lds_rd(vc, lq,      96 + hh*16); acc0 = mfma32(av, pb1, acc0);
        av = lds_rd(vc, 32 + lq, 96 + hh*16); acc1 = mfma32(av, pb1, acc1);
        __builtin_amdgcn_s_setprio(0);
      }
    }
    __syncthreads();
    cur ^= 1;
  }

  // ---- in-block flash combine: parity1 -> parity0 via LDS ----
  float* combuf = (float*)smem;
  float* cb = combuf + qhalf*34*64;
  if (par == 1) {
    cb[l] = m; cb[64 + l] = lsum;
#pragma unroll
    for (int r = 0; r < 16; ++r) {
      cb[(2+r)*64 + l]  = acc0[r];
      cb[(18+r)*64 + l] = acc1[r];
    }
  }
  __syncthreads();
  if (par == 0) {
    const float m1 = cb[l], ls1 = cb[64 + l];
    const float mm = fmaxf(m, m1);
    const float a0 = exp2f(m - mm), a1 = exp2f(m1 - mm);
    lsum = lsum*a0 + ls1*a1;
#pragma unroll
    for (int r = 0; r < 16; ++r) {
      acc0[r] = acc0[r]*a0 + cb[(2+r)*64 + l]*a1;
      acc1[r] = acc1[r]*a0 + cb[(18+r)*64 + l]*a1;
    }
    lsum += __shfl_xor(lsum, 32);
    const float inv = 1.f / lsum;

    u16* scr = &smem[2][0][0] + qhalf*2048;
#pragma unroll
    for (int dt = 0; dt < 2; ++dt)
#pragma unroll
      for (int rq = 0; rq < 4; ++rq) {
        float v0 = (dt ? acc1[4*rq+0] : acc0[4*rq+0]) * inv;
        float v1 = (dt ? acc1[4*rq+1] : acc0[4*rq+1]) * inv;
        float v2 = (dt ? acc1[4*rq+2] : acc0[4*rq+2]) * inv;
        float v3 = (dt ? acc1[4*rq+3] : acc0[4*rq+3]) * inv;
        const int dby = dt*64 + rq*16 + hh*8;
        const int by = lq*128 + (dby ^ ((lq & 7) << 4));
        *(unsigned*)((char*)scr + by)     = cvtpk(v0, v1);
        *(unsigned*)((char*)scr + by + 4) = cvtpk(v2, v3);
      }
#pragma unroll
    for (int qq = 0; qq < 4; ++qq) {
      const int qrow = qq*8 + (l >> 3);
      const int by = qrow*128 + (((l & 7) << 4) ^ ((qrow & 7) << 4));
      short8 v = *(const short8*)((const char*)scr + by);
      *(short8*)&O[(size_t)(q0w + qrow)*1024 + h*64 + (l & 7)*8] = v;
    }
  }
}

// ---------- launch ----------
extern "C" void kernel_launch(void* const* d_in, const int* in_sizes, int n_in,
                              void* d_out, int out_size, void* d_ws, size_t ws_size,
                              hipStream_t stream) {
  const float* x    = (const float*)d_in[0];
  const float* freq = (const float*)d_in[1];
  const float* wq   = (const float*)d_in[2];
  const float* wqa  = (const float*)d_in[3];
  const float* wqb  = (const float*)d_in[4];
  const float* wk   = (const float*)d_in[5];
  const float* wka  = (const float*)d_in[6];
  const float* wkb  = (const float*)d_in[7];
  const float* wv   = (const float*)d_in[8];
  const float* wva  = (const float*)d_in[9];
  const float* wvb  = (const float*)d_in[10];
  const float* wo   = (const float*)d_in[11];
  const float* wos  = (const float*)d_in[12];
  float* out = (float*)d_out;

  char* ws = (char*)d_ws;
  u16*  x_bf = (u16*)ws;
  u16*  Qb   = (u16*)ws;                  // reuses x_bf region (stream-ordered)
  u16*  Kbuf = (u16*)(ws + (4u<<20));
  u16*  Vtb  = (u16*)(ws + (5u<<20));
  u16*  W1   = (u16*)(ws + (8u<<20));
  u16*  Weff = (u16*)(ws + (9u<<20));
  float* proj = (float*)(ws + (13u<<20));
  u16*  Obf  = (u16*)(ws + (13u<<20));    // reuses proj region

  k_prep    <<<3328, 256, 0, stream>>>(x, wq, wk, wv, wqa, wka, wva, wo, wos,
                                       x_bf, W1, Weff);
  k_gemm_bt<128,64><<<dim3(4,16,4), 512, 0, stream>>>(x_bf, W1, proj, 2048, 256, 2048, 512);
  k_expand  <<<dim3(2048), 256, 0, stream>>>(proj, wqb, wkb, wvb, freq, Qb, Kbuf, Vtb);
  k_attn    <<<dim3(512), 256, 0, stream>>>(Qb, Kbuf, Vtb, Obf);
  k_gemm_bt<128,128><<<dim3(16,16,1), 512, 0, stream>>>(Obf, Weff, out, 2048, 2048, 1024, 1024);
}